// Round 16
// baseline (114.006 us; speedup 1.0000x reference)
//
#include <hip/hip_runtime.h>
#include <hip/hip_bf16.h>
#include <cstddef>

typedef __attribute__((ext_vector_type(8)))  short bf16x8;
typedef __attribute__((ext_vector_type(4)))  float f32x4;

constexpr int Bn = 4, Ln = 2048, Dn = 512, Hn = 8, DKn = 64, Mtot = 8192;
constexpr float QSCALE = 0.125f * 1.44269504088896341f;   // 1/sqrt(DK) * log2(e)
constexpr size_t HE = (size_t)Bn * Hn * Ln * DKn;          // 4,194,304
constexpr size_t WN = (size_t)Dn * Dn;                     // 262,144

__device__ inline unsigned cvt_pk_bf16(float lo, float hi) {
    unsigned r;
    asm("v_cvt_pk_bf16_f32 %0, %1, %2" : "=v"(r) : "v"(lo), "v"(hi));
    return r;
}
__device__ inline short f2bf(float x) {
    union { float f; unsigned u; } v; v.f = x;
    unsigned r = v.u + 0x7fffu + ((v.u >> 16) & 1u);
    return (short)(r >> 16);
}
__device__ inline void gl_lds16(const short* g, short* l) {
    __builtin_amdgcn_global_load_lds(
        (const __attribute__((address_space(1))) void*)g,
        (__attribute__((address_space(3))) void*)l, 16, 0, 0);
}
__device__ inline void gl_lds16f(const float* g, float* l) {
    __builtin_amdgcn_global_load_lds(
        (const __attribute__((address_space(1))) void*)g,
        (__attribute__((address_space(3))) void*)l, 16, 0, 0);
}

// ---------------------------------------------------------------------------
// Slim prep: cast 4 weights -> bf16, mask -> -1e30/0.  grid 1056 x 256.
// ---------------------------------------------------------------------------
__global__ __launch_bounds__(256) void prep_wm(
    const float* __restrict__ wq, const float* __restrict__ wk,
    const float* __restrict__ wv, const float* __restrict__ wo,
    const int* __restrict__ masks,
    short* __restrict__ Wb, float* __restrict__ maskF)
{
    size_t gid = (size_t)blockIdx.x * 256 + threadIdx.x;
    if (gid < WN) {                        // 262,144 float4s across 4 weights
        int which = (int)(gid >> 16);
        const float* src = (which == 0) ? wq : (which == 1) ? wk : (which == 2) ? wv : wo;
        size_t i4 = gid & 65535;
        float4 xv = *(const float4*)&src[i4 * 4];
        uint2 p = {cvt_pk_bf16(xv.x, xv.y), cvt_pk_bf16(xv.z, xv.w)};
        *(uint2*)&Wb[(size_t)which * WN + i4 * 4] = p;
    } else {
        size_t mi = gid - WN;
        if (mi < (size_t)Bn * Ln) maskF[mi] = (masks[mi] == 0) ? -1e30f : 0.f;
    }
}

__global__ __launch_bounds__(256) void mask_prep(
    const int* __restrict__ masks, float* __restrict__ maskF)
{
    int i = blockIdx.x * 256 + threadIdx.x;
    if (i < Bn * Ln) maskF[i] = (masks[i] == 0) ? -1e30f : 0.f;
}

// ---------------------------------------------------------------------------
// QKV projection: A staged as FP32 via DMA (no pre-cast pass), converted to
// bf16 at fragment read; B = bf16 weights via DMA.  C = X @ W^T + b.
// A swizzle (both sides, 8-float granularity): src col = (col4*4)^(8*(row&7)),
// read off = (g*8+c*32)^(8*(row&7)).  Tile 128x128, BK=64, 8 K-steps.
// grid (64, 4, 3) x 256.  LDS 48 KB.
// ---------------------------------------------------------------------------
__global__ __launch_bounds__(256) void qkv_proj_f32(
    const float* __restrict__ q, const float* __restrict__ k, const float* __restrict__ v,
    const short* __restrict__ Wb,
    const float* __restrict__ bq, const float* __restrict__ bk, const float* __restrict__ bv,
    short* __restrict__ Qh, short* __restrict__ Kh, short* __restrict__ Vt)
{
    const int p = blockIdx.z;
    const float* X    = (p == 0) ? q : (p == 1) ? k : v;
    const short* W    = Wb + (size_t)p * WN;
    const float* bias = (p == 0) ? bq : (p == 1) ? bk : bv;
    short*       O    = (p == 0) ? Qh : (p == 1) ? Kh : Vt;
    const float scl   = (p == 0) ? QSCALE : 1.0f;

    __shared__ float Af[128 * 64];   // 32 KB
    __shared__ short Bs[128 * 64];   // 16 KB

    const int tid  = threadIdx.x;
    const int lane = tid & 63, w = tid >> 6;
    const int wr = w >> 1, wc = w & 1;
    const int l16 = lane & 15, g = lane >> 4;
    const int m0 = blockIdx.x * 128, n0 = blockIdx.y * 128;

    // A staging: chunk c = tid + 256f (f<8): row = (tid>>4)+16f, col4 = tid&15
    const int rA = tid >> 4, col4 = tid & 15;
    const int scolA = (col4 * 4) ^ (8 * (rA & 7));      // row&7 invariant across f
    const float* Ag = X + (size_t)(m0 + rA) * Dn + scolA;
    // B staging: chunk c = tid + 256f (f<4): row = (tid>>3)+32f, col8 = tid&7
    const int rB = tid >> 3, c8 = tid & 7;
    const int scolB = ((c8 ^ (rB & 7)) << 3);
    const short* Bg = W + (size_t)(n0 + rB) * Dn + scolB;

    f32x4 acc[4][4];
    #pragma unroll
    for (int i = 0; i < 4; ++i)
        #pragma unroll
        for (int j = 0; j < 4; ++j)
            acc[i][j] = (f32x4){0.f, 0.f, 0.f, 0.f};

    for (int ks = 0; ks < 8; ++ks) {
        #pragma unroll
        for (int f = 0; f < 8; ++f)
            gl_lds16f(Ag + (size_t)f * 16 * Dn, &Af[(w * 64 + 256 * f) * 4]);
        #pragma unroll
        for (int f = 0; f < 4; ++f)
            gl_lds16(Bg + (size_t)f * 32 * Dn, &Bs[(w * 64 + 256 * f) * 8]);
        Ag += 64; Bg += 64;
        __syncthreads();

        bf16x8 bfv[4][2];
        #pragma unroll
        for (int j = 0; j < 4; ++j) {
            int row = wc * 64 + j * 16 + l16;
            int sw = (row & 7) << 3;
            bfv[j][0] = *(const bf16x8*)&Bs[row * 64 + ((g * 8) ^ sw)];
            bfv[j][1] = *(const bf16x8*)&Bs[row * 64 + ((32 + g * 8) ^ sw)];
        }
        #pragma unroll
        for (int i = 0; i < 4; ++i) {
            int row = wr * 64 + i * 16 + l16;
            int m8 = 8 * (row & 7);
            bf16x8 a[2];
            #pragma unroll
            for (int c = 0; c < 2; ++c) {
                int base = row * 64 + ((g * 8 + c * 32) ^ m8);
                f32x4 x0 = *(const f32x4*)&Af[base];
                f32x4 x1 = *(const f32x4*)&Af[base + 4];
                union { unsigned u[4]; bf16x8 v; } pu;
                pu.u[0] = cvt_pk_bf16(x0[0], x0[1]);
                pu.u[1] = cvt_pk_bf16(x0[2], x0[3]);
                pu.u[2] = cvt_pk_bf16(x1[0], x1[1]);
                pu.u[3] = cvt_pk_bf16(x1[2], x1[3]);
                a[c] = pu.v;
            }
            #pragma unroll
            for (int j = 0; j < 4; ++j) {
                acc[i][j] = __builtin_amdgcn_mfma_f32_16x16x32_bf16(a[0], bfv[j][0], acc[i][j], 0, 0, 0);
                acc[i][j] = __builtin_amdgcn_mfma_f32_16x16x32_bf16(a[1], bfv[j][1], acc[i][j], 0, 0, 0);
            }
        }
        __syncthreads();
    }

    const int bb = m0 >> 11;
    #pragma unroll
    for (int i = 0; i < 4; ++i) {
        #pragma unroll
        for (int j = 0; j < 4; ++j) {
            int n  = n0 + wc * 64 + j * 16 + l16;
            int h  = n >> 6, dk = n & 63;
            float bval = bias[n];
            #pragma unroll
            for (int r = 0; r < 4; ++r) {
                int m  = m0 + wr * 64 + i * 16 + g * 4 + r;
                int lq = m & (Ln - 1);
                short val = f2bf((acc[i][j][r] + bval) * scl);
                if (p < 2)
                    O[(((size_t)bb * Hn + h) * Ln + lq) * DKn + dk] = val;
                else
                    O[(((size_t)bb * Hn + h) * DKn + dk) * Ln + lq] = val;
            }
        }
    }
}

// ---------------------------------------------------------------------------
// Output projection, 64x64 tile, DMA-staged bf16 GEMM.  grid (128, 8) x 256.
// ---------------------------------------------------------------------------
__global__ __launch_bounds__(256) void out_proj_bf16(
    const short* __restrict__ Ctx, const short* __restrict__ Wo,
    const float* __restrict__ bias, float* __restrict__ Out)
{
    __shared__ short As[64 * 64];
    __shared__ short Bs[64 * 64];

    const int tid  = threadIdx.x;
    const int lane = tid & 63, w = tid >> 6;
    const int wr = w >> 1, wc = w & 1;
    const int l16 = lane & 15, g = lane >> 4;
    const int m0 = blockIdx.x * 64, n0 = blockIdx.y * 64;

    const short* Ag[2]; const short* Bg[2]; int ldsOff[2];
    #pragma unroll
    for (int f = 0; f < 2; ++f) {
        int c = tid + 256 * f;
        int row = c >> 3, col8 = c & 7;
        int scolw = ((col8 ^ (row & 7)) << 3);
        Ag[f] = Ctx + (size_t)(m0 + row) * Dn + scolw;
        Bg[f] = Wo  + (size_t)(n0 + row) * Dn + scolw;
        ldsOff[f] = (w * 64 + 256 * f) * 8;
    }

    f32x4 acc[2][2];
    #pragma unroll
    for (int i = 0; i < 2; ++i)
        #pragma unroll
        for (int j = 0; j < 2; ++j)
            acc[i][j] = (f32x4){0.f, 0.f, 0.f, 0.f};

    for (int ks = 0; ks < 8; ++ks) {
        #pragma unroll
        for (int f = 0; f < 2; ++f) {
            gl_lds16(Ag[f], &As[ldsOff[f]]);
            gl_lds16(Bg[f], &Bs[ldsOff[f]]);
            Ag[f] += 64; Bg[f] += 64;
        }
        __syncthreads();

        bf16x8 bfv[2][2];
        #pragma unroll
        for (int j = 0; j < 2; ++j) {
            int row = wc * 32 + j * 16 + l16;
            int sw = (row & 7) << 3;
            bfv[j][0] = *(const bf16x8*)&Bs[row * 64 + ((g * 8) ^ sw)];
            bfv[j][1] = *(const bf16x8*)&Bs[row * 64 + ((32 + g * 8) ^ sw)];
        }
        #pragma unroll
        for (int i = 0; i < 2; ++i) {
            int row = wr * 32 + i * 16 + l16;
            int sw = (row & 7) << 3;
            bf16x8 a0 = *(const bf16x8*)&As[row * 64 + ((g * 8) ^ sw)];
            bf16x8 a1 = *(const bf16x8*)&As[row * 64 + ((32 + g * 8) ^ sw)];
            #pragma unroll
            for (int j = 0; j < 2; ++j) {
                acc[i][j] = __builtin_amdgcn_mfma_f32_16x16x32_bf16(a0, bfv[j][0], acc[i][j], 0, 0, 0);
                acc[i][j] = __builtin_amdgcn_mfma_f32_16x16x32_bf16(a1, bfv[j][1], acc[i][j], 0, 0, 0);
            }
        }
        __syncthreads();
    }

    #pragma unroll
    for (int i = 0; i < 2; ++i) {
        #pragma unroll
        for (int j = 0; j < 2; ++j) {
            int n = n0 + wc * 32 + j * 16 + l16;
            float bval = bias[n];
            #pragma unroll
            for (int r = 0; r < 4; ++r) {
                int m = m0 + wr * 32 + i * 16 + g * 4 + r;
                Out[(size_t)m * Dn + n] = acc[i][j][r] + bval;
            }
        }
    }
}

// ---------------------------------------------------------------------------
// Flash attention (R15, unchanged): 16x16x32 bf16 MFMA, swapped QK^T, O^T,
// no-max softmax, MFMA row sums, kc-permuted K (P in registers), DMA staging,
// XCD grid swizzle, MF=2 + in-block KV-split, linear merge.
// ---------------------------------------------------------------------------
__global__ __launch_bounds__(256, 3) void attn_mfma(
    const short* __restrict__ Qh, const short* __restrict__ Kh, const short* __restrict__ Vt,
    const float* __restrict__ maskF, short* __restrict__ Ctx)
{
    __shared__ short smem[16384];

    const int tid  = threadIdx.x;
    const int lane = tid & 63, w = tid >> 6;
    const int l16 = lane & 15, g = lane >> 4;
    const int qt = w & 1, hf = w >> 1;

    const int bid = blockIdx.x;
    const int id  = (bid & 7) * 128 + (bid >> 3);
    const int qb  = id & 31;
    const int bh  = id >> 5;
    const int bb  = bh >> 3, hd = bh & 7;
    const int q0  = qb * 64;
    constexpr int NT = 32;

    const short* Qp = Qh + (size_t)bh * Ln * DKn;
    const short* Kp = Kh + (size_t)bh * Ln * DKn;
    const short* Vp = Vt + (size_t)bh * DKn * Ln;
    const float* mp = maskF + bb * Ln + hf * 1024;

    bf16x8 qf[2][2];
    #pragma unroll
    for (int mf = 0; mf < 2; ++mf)
        #pragma unroll
        for (int c = 0; c < 2; ++c)
            qf[mf][c] = *(const bf16x8*)&Qp[(size_t)(q0 + qt * 32 + mf * 16 + l16) * DKn + c * 32 + g * 8];

    constexpr short BF1 = (short)0x3F80;
    const bf16x8 ones = {BF1, BF1, BF1, BF1, BF1, BF1, BF1, BF1};

    const short* kg[2]; const short* vg[2]; int sbk[2];
    #pragma unroll
    for (int j = 0; j < 2; ++j) {
        int sb = qt * 2 + j;
        sbk[j] = sb * 512;
        int p  = sb * 8 + (lane >> 3);
        int kc = ((p & 0x0C) << 1) | ((p & 0x10) >> 2) | (p & 3);
        int scol = ((lane & 7) ^ (p & 7)) << 3;
        kg[j] = Kp + (size_t)(hf * 1024 + kc) * DKn + scol;
        int vrow = sb * 16 + (lane >> 2);
        int scolv = (((lane & 3) ^ (vrow & 3)) << 3);
        vg[j] = Vp + (size_t)vrow * Ln + hf * 1024 + scolv;
    }

    int kofs[2][2];
    #pragma unroll
    for (int kt = 0; kt < 2; ++kt) {
        int row = kt * 16 + l16;
        kofs[kt][0] = row * 64 + ((g * 8) ^ ((row & 7) << 3));
        kofs[kt][1] = row * 64 + ((32 + g * 8) ^ ((row & 7) << 3));
    }
    int vofs[4];
    #pragma unroll
    for (int d = 0; d < 4; ++d)
        vofs[d] = (d * 16 + l16) * 32 + ((g * 8) ^ ((l16 & 3) << 3));

    f32x4 oacc[2][4];
    #pragma unroll
    for (int mf = 0; mf < 2; ++mf)
        #pragma unroll
        for (int d = 0; d < 4; ++d) oacc[mf][d] = (f32x4){0.f, 0.f, 0.f, 0.f};
    f32x4 lsum[2] = {(f32x4){0.f, 0.f, 0.f, 0.f}, (f32x4){0.f, 0.f, 0.f, 0.f}};

    #pragma unroll
    for (int j = 0; j < 2; ++j) {
        gl_lds16(kg[j], smem + hf * 4096 + sbk[j]);
        gl_lds16(vg[j], smem + 8192 + hf * 4096 + sbk[j]);
    }
    __syncthreads();

    int cb = 0;
    for (int t = 0; t < NT; ++t) {
        if (t < NT - 1) {
            const int ko = (t + 1) * 2048;
            const int vo = (t + 1) * 32;
            short* kd = smem + (hf * 2 + (cb ^ 1)) * 2048;
            short* vd = smem + 8192 + (hf * 2 + (cb ^ 1)) * 2048;
            #pragma unroll
            for (int j = 0; j < 2; ++j) {
                gl_lds16(kg[j] + ko, kd + sbk[j]);
                gl_lds16(vg[j] + vo, vd + sbk[j]);
            }
        }
        const short* Kb = smem + (hf * 2 + cb) * 2048;
        const short* Vb = smem + 8192 + (hf * 2 + cb) * 2048;

        f32x4 mk[2];
        mk[0] = *(const f32x4*)&mp[t * 32 + 8 * g];
        mk[1] = *(const f32x4*)&mp[t * 32 + 8 * g + 4];

        bf16x8 kf[2][2];
        #pragma unroll
        for (int kt = 0; kt < 2; ++kt) {
            kf[kt][0] = *(const bf16x8*)&Kb[kofs[kt][0]];
            kf[kt][1] = *(const bf16x8*)&Kb[kofs[kt][1]];
        }

        f32x4 sv[2][2];
        __builtin_amdgcn_s_setprio(1);
        #pragma unroll
        for (int mf = 0; mf < 2; ++mf)
            #pragma unroll
            for (int kt = 0; kt < 2; ++kt) {
                f32x4 z = __builtin_amdgcn_mfma_f32_16x16x32_bf16(kf[kt][0], qf[mf][0], mk[kt], 0, 0, 0);
                z = __builtin_amdgcn_mfma_f32_16x16x32_bf16(kf[kt][1], qf[mf][1], z, 0, 0, 0);
                sv[mf][kt] = z;
            }
        __builtin_amdgcn_s_setprio(0);

        bf16x8 pf[2];
        #pragma unroll
        for (int mf = 0; mf < 2; ++mf) {
            float e0 = exp2f(sv[mf][0][0]), e1 = exp2f(sv[mf][0][1]);
            float e2 = exp2f(sv[mf][0][2]), e3 = exp2f(sv[mf][0][3]);
            float e4 = exp2f(sv[mf][1][0]), e5 = exp2f(sv[mf][1][1]);
            float e6 = exp2f(sv[mf][1][2]), e7 = exp2f(sv[mf][1][3]);
            union { unsigned u[4]; bf16x8 v; } pu;
            pu.u[0] = cvt_pk_bf16(e0, e1);
            pu.u[1] = cvt_pk_bf16(e2, e3);
            pu.u[2] = cvt_pk_bf16(e4, e5);
            pu.u[3] = cvt_pk_bf16(e6, e7);
            pf[mf] = pu.v;
        }

        bf16x8 vf[4];
        #pragma unroll
        for (int d = 0; d < 4; ++d)
            vf[d] = *(const bf16x8*)&Vb[vofs[d]];

        __builtin_amdgcn_s_setprio(1);
        #pragma unroll
        for (int mf = 0; mf < 2; ++mf) {
            lsum[mf] = __builtin_amdgcn_mfma_f32_16x16x32_bf16(ones, pf[mf], lsum[mf], 0, 0, 0);
            #pragma unroll
            for (int d = 0; d < 4; ++d)
                oacc[mf][d] = __builtin_amdgcn_mfma_f32_16x16x32_bf16(vf[d], pf[mf], oacc[mf][d], 0, 0, 0);
        }
        __builtin_amdgcn_s_setprio(0);

        __syncthreads();
        cb ^= 1;
    }

    float* M = (float*)smem;
    if (hf == 1) {
        #pragma unroll
        for (int mf = 0; mf < 2; ++mf) {
            int ql = qt * 32 + mf * 16 + l16;
            #pragma unroll
            for (int d = 0; d < 4; ++d)
                *(f32x4*)&M[ql * 68 + d * 16 + g * 4] = oacc[mf][d];
            if (g == 0) M[ql * 68 + 64] = lsum[mf][0];
        }
    }
    __syncthreads();
    if (hf == 0) {
        #pragma unroll
        for (int mf = 0; mf < 2; ++mf) {
            int ql = qt * 32 + mf * 16 + l16;
            float lt = lsum[mf][0] + M[ql * 68 + 64];
            float inv = 1.0f / lt;
            size_t mrow = (size_t)bb * Ln + q0 + ql;
            #pragma unroll
            for (int d = 0; d < 4; ++d) {
                f32x4 ob = *(const f32x4*)&M[ql * 68 + d * 16 + g * 4];
                float o0 = (oacc[mf][d][0] + ob[0]) * inv;
                float o1 = (oacc[mf][d][1] + ob[1]) * inv;
                float o2 = (oacc[mf][d][2] + ob[2]) * inv;
                float o3 = (oacc[mf][d][3] + ob[3]) * inv;
                uint2 pr = {cvt_pk_bf16(o0, o1), cvt_pk_bf16(o2, o3)};
                *(uint2*)&Ctx[mrow * Dn + hd * 64 + d * 16 + g * 4] = pr;
            }
        }
    }
}

// ---------------------------------------------------------------------------
// Fallback kernels (fp32-input projections) for small workspaces.
// ---------------------------------------------------------------------------
__global__ __launch_bounds__(256) void qkv_proj_mfma(
    const float* __restrict__ q, const float* __restrict__ k, const float* __restrict__ v,
    const float* __restrict__ wq, const float* __restrict__ wk, const float* __restrict__ wv,
    const float* __restrict__ bq, const float* __restrict__ bk, const float* __restrict__ bv,
    short* __restrict__ Qh, short* __restrict__ Kh, short* __restrict__ Vt)
{
    const int p = blockIdx.z;
    const float* X    = (p == 0) ? q  : (p == 1) ? k  : v;
    const float* W    = (p == 0) ? wq : (p == 1) ? wk : wv;
    const float* bias = (p == 0) ? bq : (p == 1) ? bk : bv;
    short*       O    = (p == 0) ? Qh : (p == 1) ? Kh : Vt;
    const float scl   = (p == 0) ? QSCALE : 1.0f;

    __shared__ short As[128 * 72];
    __shared__ short Bs[128 * 72];

    const int tid  = threadIdx.x;
    const int lane = tid & 63, w = tid >> 6;
    const int wr = w >> 1, wc = w & 1;
    const int l16 = lane & 15, g = lane >> 4;
    const int m0 = blockIdx.x * 128, n0 = blockIdx.y * 128;

    f32x4 acc[4][4];
    #pragma unroll
    for (int i = 0; i < 4; ++i)
        #pragma unroll
        for (int j = 0; j < 4; ++j)
            acc[i][j] = (f32x4){0.f, 0.f, 0.f, 0.f};

    for (int k0 = 0; k0 < Dn; k0 += 64) {
        #pragma unroll
        for (int f = 0; f < 8; ++f) {
            int lin = tid + 256 * f;
            int row = lin >> 4, c4 = lin & 15;
            float4 xv = *(const float4*)&X[(size_t)(m0 + row) * Dn + k0 + c4 * 4];
            uint2 xp = {cvt_pk_bf16(xv.x, xv.y), cvt_pk_bf16(xv.z, xv.w)};
            *(uint2*)&As[row * 72 + c4 * 4] = xp;
            float4 wv4 = *(const float4*)&W[(size_t)(n0 + row) * Dn + k0 + c4 * 4];
            uint2 wp = {cvt_pk_bf16(wv4.x, wv4.y), cvt_pk_bf16(wv4.z, wv4.w)};
            *(uint2*)&Bs[row * 72 + c4 * 4] = wp;
        }
        __syncthreads();

        bf16x8 af[4][2], bfv[4][2];
        #pragma unroll
        for (int i = 0; i < 4; ++i)
            #pragma unroll
            for (int c = 0; c < 2; ++c)
                af[i][c] = *(const bf16x8*)&As[(wr * 64 + i * 16 + l16) * 72 + c * 32 + g * 8];
        #pragma unroll
        for (int j = 0; j < 4; ++j)
            #pragma unroll
            for (int c = 0; c < 2; ++c)
                bfv[j][c] = *(const bf16x8*)&Bs[(wc * 64 + j * 16 + l16) * 72 + c * 32 + g * 8];

        #pragma unroll
        for (int i = 0; i < 4; ++i)
            #pragma unroll
            for (int j = 0; j < 4; ++j) {
                acc[i][j] = __builtin_amdgcn_mfma_f32_16x16x32_bf16(af[i][0], bfv[j][0], acc[i][j], 0, 0, 0);
                acc[i][j] = __builtin_amdgcn_mfma_f32_16x16x32_bf16(af[i][1], bfv[j][1], acc[i][j], 0, 0, 0);
            }
        __syncthreads();
    }

    const int bb = m0 >> 11;
    #pragma unroll
    for (int i = 0; i < 4; ++i) {
        #pragma unroll
        for (int j = 0; j < 4; ++j) {
            int n  = n0 + wc * 64 + j * 16 + l16;
            int h  = n >> 6, dk = n & 63;
            float bval = bias[n];
            #pragma unroll
            for (int r = 0; r < 4; ++r) {
                int m  = m0 + wr * 64 + i * 16 + g * 4 + r;
                int lq = m & (Ln - 1);
                short val = f2bf((acc[i][j][r] + bval) * scl);
                if (p < 2)
                    O[(((size_t)bb * Hn + h) * Ln + lq) * DKn + dk] = val;
                else
                    O[(((size_t)bb * Hn + h) * DKn + dk) * Ln + lq] = val;
            }
        }
    }
}

__global__ __launch_bounds__(256) void out_proj_mfma(
    const short* __restrict__ Ctx, const float* __restrict__ W,
    const float* __restrict__ bias, float* __restrict__ Out)
{
    __shared__ short As[128 * 72];
    __shared__ short Bs[128 * 72];

    const int tid  = threadIdx.x;
    const int lane = tid & 63, w = tid >> 6;
    const int wr = w >> 1, wc = w & 1;
    const int l16 = lane & 15, g = lane >> 4;
    const int m0 = blockIdx.x * 128, n0 = blockIdx.y * 128;

    f32x4 acc[4][4];
    #pragma unroll
    for (int i = 0; i < 4; ++i)
        #pragma unroll
        for (int j = 0; j < 4; ++j)
            acc[i][j] = (f32x4){0.f, 0.f, 0.f, 0.f};

    for (int k0 = 0; k0 < Dn; k0 += 64) {
        #pragma unroll
        for (int f = 0; f < 4; ++f) {
            int lin = tid + 256 * f;
            int row = lin >> 3, c8 = lin & 7;
            bf16x8 av = *(const bf16x8*)&Ctx[(size_t)(m0 + row) * Dn + k0 + c8 * 8];
            *(bf16x8*)&As[row * 72 + c8 * 8] = av;
        }
        #pragma unroll
        for (int f = 0; f < 8; ++f) {
            int lin = tid + 256 * f;
            int row = lin >> 4, c4 = lin & 15;
            float4 wv4 = *(const float4*)&W[(size_t)(n0 + row) * Dn + k0 + c4 * 4];
            uint2 wp = {cvt_pk_bf16(wv4.x, wv4.y), cvt_pk_bf16(wv4.z, wv4.w)};
            *(uint2*)&Bs[row * 72 + c4 * 4] = wp;
        }
        __syncthreads();

        bf16x8 af[4][2], bfv[4][2];
        #pragma unroll
        for (int i = 0; i < 4; ++i)
            #pragma unroll
            for (int c = 0; c < 2; ++c)
                af[i][c] = *(const bf16x8*)&As[(wr * 64 + i * 16 + l16) * 72 + c * 32 + g * 8];
        #pragma unroll
        for (int j = 0; j < 4; ++j)
            #pragma unroll
            for (int c = 0; c < 2; ++c)
                bfv[j][c] = *(const bf16x8*)&Bs[(wc * 64 + j * 16 + l16) * 72 + c * 32 + g * 8];

        #pragma unroll
        for (int i = 0; i < 4; ++i)
            #pragma unroll
            for (int j = 0; j < 4; ++j) {
                acc[i][j] = __builtin_amdgcn_mfma_f32_16x16x32_bf16(af[i][0], bfv[j][0], acc[i][j], 0, 0, 0);
                acc[i][j] = __builtin_amdgcn_mfma_f32_16x16x32_bf16(af[i][1], bfv[j][1], acc[i][j], 0, 0, 0);
            }
        __syncthreads();
    }

    #pragma unroll
    for (int i = 0; i < 4; ++i) {
        #pragma unroll
        for (int j = 0; j < 4; ++j) {
            int n = n0 + wc * 64 + j * 16 + l16;
            float bval = bias[n];
            #pragma unroll
            for (int r = 0; r < 4; ++r) {
                int m = m0 + wr * 64 + i * 16 + g * 4 + r;
                Out[(size_t)m * Dn + n] = acc[i][j][r] + bval;
            }
        }
    }
}

// ---------------------------------------------------------------------------
extern "C" void kernel_launch(void* const* d_in, const int* in_sizes, int n_in,
                              void* d_out, int out_size, void* d_ws, size_t ws_size,
                              hipStream_t stream)
{
    (void)in_sizes; (void)n_in; (void)out_size;
    const float* q    = (const float*)d_in[0];
    const float* k    = (const float*)d_in[1];
    const float* v    = (const float*)d_in[2];
    const int*   mks  = (const int*)  d_in[3];
    const float* wq_w = (const float*)d_in[4];
    const float* wq_b = (const float*)d_in[5];
    const float* wk_w = (const float*)d_in[6];
    const float* wk_b = (const float*)d_in[7];
    const float* wv_w = (const float*)d_in[8];
    const float* wv_b = (const float*)d_in[9];
    const float* wo_w = (const float*)d_in[10];
    const float* wo_b = (const float*)d_in[11];
    float* out = (float*)d_out;

    short* ws = (short*)d_ws;
    const size_t needed = (4 * HE + 4 * WN + 2 * (size_t)Bn * Ln) * 2;   // ~36 MiB

    if (ws_size >= needed) {
        short* Qh   = ws;
        short* Kh   = ws + HE;
        short* Vt   = ws + 2 * HE;
        short* Ctx  = ws + 3 * HE;
        short* Wb   = ws + 4 * HE;           // 4*WN
        float* maskF = (float*)(ws + 4 * HE + 4 * WN);

        const int prepBlocks = (int)((WN + (size_t)Bn * Ln + 255) / 256);
        prep_wm<<<dim3(prepBlocks), 256, 0, stream>>>(
            wq_w, wk_w, wv_w, wo_w, mks, Wb, maskF);

        qkv_proj_f32<<<dim3(64, 4, 3), 256, 0, stream>>>(
            q, k, v, Wb, wq_b, wk_b, wv_b, Qh, Kh, Vt);

        attn_mfma<<<dim3(1024), 256, 0, stream>>>(Qh, Kh, Vt, maskF, Ctx);

        out_proj_bf16<<<dim3(128, 8), 256, 0, stream>>>(Ctx, Wb + 3 * WN, wo_b, out);
    } else {
        short* Qh  = ws;
        short* Kh  = ws + HE;
        short* Vt  = ws + 2 * HE;
        short* Ctx = ws + 3 * HE;
        float* maskF = (float*)(ws + 4 * HE);

        mask_prep<<<dim3(32), 256, 0, stream>>>(mks, maskF);
        qkv_proj_mfma<<<dim3(Mtot / 128, Dn / 128, 3), 256, 0, stream>>>(
            q, k, v, wq_w, wk_w, wv_w, wq_b, wk_b, wv_b, Qh, Kh, Vt);
        attn_mfma<<<dim3(1024), 256, 0, stream>>>(Qh, Kh, Vt, maskF, Ctx);
        out_proj_mfma<<<dim3(Mtot / 128, Dn / 128), 256, 0, stream>>>(Ctx, wo_w, wo_b, out);
    }
}

// Round 17
// 108.996 us; speedup vs baseline: 1.0460x; 1.0460x over previous
//
#include <hip/hip_runtime.h>
#include <hip/hip_bf16.h>
#include <cstddef>

typedef __attribute__((ext_vector_type(8)))  short bf16x8;
typedef __attribute__((ext_vector_type(4)))  float f32x4;

constexpr int Bn = 4, Ln = 2048, Dn = 512, Hn = 8, DKn = 64, Mtot = 8192;
constexpr float QSCALE = 0.125f * 1.44269504088896341f;   // 1/sqrt(DK) * log2(e)
constexpr size_t HE = (size_t)Bn * Hn * Ln * DKn;          // 4,194,304
constexpr size_t WN = (size_t)Dn * Dn;                     // 262,144

__device__ inline unsigned cvt_pk_bf16(float lo, float hi) {
    unsigned r;
    asm("v_cvt_pk_bf16_f32 %0, %1, %2" : "=v"(r) : "v"(lo), "v"(hi));
    return r;
}
__device__ inline short f2bf(float x) {
    union { float f; unsigned u; } v; v.f = x;
    unsigned r = v.u + 0x7fffu + ((v.u >> 16) & 1u);
    return (short)(r >> 16);
}
__device__ inline void gl_lds16(const short* g, short* l) {
    __builtin_amdgcn_global_load_lds(
        (const __attribute__((address_space(1))) void*)g,
        (__attribute__((address_space(3))) void*)l, 16, 0, 0);
}
__device__ inline void gl_lds16f(const float* g, float* l) {
    __builtin_amdgcn_global_load_lds(
        (const __attribute__((address_space(1))) void*)g,
        (__attribute__((address_space(3))) void*)l, 16, 0, 0);
}

// ---------------------------------------------------------------------------
// Slim prep: cast 4 weights -> bf16, mask -> -1e30/0.  grid 1056 x 256.
// ---------------------------------------------------------------------------
__global__ __launch_bounds__(256) void prep_wm(
    const float* __restrict__ wq, const float* __restrict__ wk,
    const float* __restrict__ wv, const float* __restrict__ wo,
    const int* __restrict__ masks,
    short* __restrict__ Wb, float* __restrict__ maskF)
{
    size_t gid = (size_t)blockIdx.x * 256 + threadIdx.x;
    if (gid < WN) {                        // 262,144 float4s across 4 weights
        int which = (int)(gid >> 16);
        const float* src = (which == 0) ? wq : (which == 1) ? wk : (which == 2) ? wv : wo;
        size_t i4 = gid & 65535;
        float4 xv = *(const float4*)&src[i4 * 4];
        uint2 p = {cvt_pk_bf16(xv.x, xv.y), cvt_pk_bf16(xv.z, xv.w)};
        *(uint2*)&Wb[(size_t)which * WN + i4 * 4] = p;
    } else {
        size_t mi = gid - WN;
        if (mi < (size_t)Bn * Ln) maskF[mi] = (masks[mi] == 0) ? -1e30f : 0.f;
    }
}

__global__ __launch_bounds__(256) void mask_prep(
    const int* __restrict__ masks, float* __restrict__ maskF)
{
    int i = blockIdx.x * 256 + threadIdx.x;
    if (i < Bn * Ln) maskF[i] = (masks[i] == 0) ? -1e30f : 0.f;
}

// ---------------------------------------------------------------------------
// QKV projection v17: BM=64 x BN=128 tile (1536 blocks, 5/CU resident).
// A staged as FP32 via DMA, converted at fragment read; B bf16 via DMA.
// LDS 32 KB.  grid (128, 4, 3) x 256, 8 K-steps.
// ---------------------------------------------------------------------------
__global__ __launch_bounds__(256) void qkv_proj_f32(
    const float* __restrict__ q, const float* __restrict__ k, const float* __restrict__ v,
    const short* __restrict__ Wb,
    const float* __restrict__ bq, const float* __restrict__ bk, const float* __restrict__ bv,
    short* __restrict__ Qh, short* __restrict__ Kh, short* __restrict__ Vt)
{
    const int p = blockIdx.z;
    const float* X    = (p == 0) ? q : (p == 1) ? k : v;
    const short* W    = Wb + (size_t)p * WN;
    const float* bias = (p == 0) ? bq : (p == 1) ? bk : bv;
    short*       O    = (p == 0) ? Qh : (p == 1) ? Kh : Vt;
    const float scl   = (p == 0) ? QSCALE : 1.0f;

    __shared__ float Af[64 * 64];    // 16 KB
    __shared__ short Bs[128 * 64];   // 16 KB

    const int tid  = threadIdx.x;
    const int lane = tid & 63, w = tid >> 6;
    const int wr = w >> 1, wc = w & 1;
    const int l16 = lane & 15, g = lane >> 4;
    const int m0 = blockIdx.x * 64, n0 = blockIdx.y * 128;

    // A staging: 1024 chunks (16B), 4/thread.  chunk c = tid + 256f:
    // rowA = (tid>>4) + 16f, col4 = tid&15; rowA&7 invariant across f.
    const int rA = tid >> 4, col4 = tid & 15;
    const int scolA = (col4 * 4) ^ (8 * (rA & 7));
    const float* Ag = X + (size_t)(m0 + rA) * Dn + scolA;
    // B staging: 1024 chunks (8 shorts), 4/thread.  rowB = (tid>>3) + 32f.
    const int rB = tid >> 3, c8 = tid & 7;
    const int scolB = ((c8 ^ (rB & 7)) << 3);
    const short* Bg = W + (size_t)(n0 + rB) * Dn + scolB;

    f32x4 acc[2][4];
    #pragma unroll
    for (int i = 0; i < 2; ++i)
        #pragma unroll
        for (int j = 0; j < 4; ++j)
            acc[i][j] = (f32x4){0.f, 0.f, 0.f, 0.f};

    for (int ks = 0; ks < 8; ++ks) {
        #pragma unroll
        for (int f = 0; f < 4; ++f)
            gl_lds16f(Ag + (size_t)f * 16 * Dn, &Af[(w * 64 + 256 * f) * 4]);
        #pragma unroll
        for (int f = 0; f < 4; ++f)
            gl_lds16(Bg + (size_t)f * 32 * Dn, &Bs[(w * 64 + 256 * f) * 8]);
        Ag += 64; Bg += 64;
        __syncthreads();

        bf16x8 bfv[4][2];
        #pragma unroll
        for (int j = 0; j < 4; ++j) {
            int row = wc * 64 + j * 16 + l16;
            int sw = (row & 7) << 3;
            bfv[j][0] = *(const bf16x8*)&Bs[row * 64 + ((g * 8) ^ sw)];
            bfv[j][1] = *(const bf16x8*)&Bs[row * 64 + ((32 + g * 8) ^ sw)];
        }
        #pragma unroll
        for (int i = 0; i < 2; ++i) {
            int row = wr * 32 + i * 16 + l16;
            int m8 = 8 * (row & 7);
            bf16x8 a[2];
            #pragma unroll
            for (int c = 0; c < 2; ++c) {
                int base = row * 64 + ((g * 8 + c * 32) ^ m8);
                f32x4 x0 = *(const f32x4*)&Af[base];
                f32x4 x1 = *(const f32x4*)&Af[base + 4];
                union { unsigned u[4]; bf16x8 v; } pu;
                pu.u[0] = cvt_pk_bf16(x0[0], x0[1]);
                pu.u[1] = cvt_pk_bf16(x0[2], x0[3]);
                pu.u[2] = cvt_pk_bf16(x1[0], x1[1]);
                pu.u[3] = cvt_pk_bf16(x1[2], x1[3]);
                a[c] = pu.v;
            }
            #pragma unroll
            for (int j = 0; j < 4; ++j) {
                acc[i][j] = __builtin_amdgcn_mfma_f32_16x16x32_bf16(a[0], bfv[j][0], acc[i][j], 0, 0, 0);
                acc[i][j] = __builtin_amdgcn_mfma_f32_16x16x32_bf16(a[1], bfv[j][1], acc[i][j], 0, 0, 0);
            }
        }
        __syncthreads();
    }

    const int bb = m0 >> 11;
    #pragma unroll
    for (int i = 0; i < 2; ++i) {
        #pragma unroll
        for (int j = 0; j < 4; ++j) {
            int n  = n0 + wc * 64 + j * 16 + l16;
            int h  = n >> 6, dk = n & 63;
            float bval = bias[n];
            #pragma unroll
            for (int r = 0; r < 4; ++r) {
                int m  = m0 + wr * 32 + i * 16 + g * 4 + r;
                int lq = m & (Ln - 1);
                short val = f2bf((acc[i][j][r] + bval) * scl);
                if (p < 2)
                    O[(((size_t)bb * Hn + h) * Ln + lq) * DKn + dk] = val;
                else
                    O[(((size_t)bb * Hn + h) * DKn + dk) * Ln + lq] = val;
            }
        }
    }
}

// ---------------------------------------------------------------------------
// Output projection, 64x64 tile, DMA-staged bf16 GEMM.  grid (128, 8) x 256.
// ---------------------------------------------------------------------------
__global__ __launch_bounds__(256) void out_proj_bf16(
    const short* __restrict__ Ctx, const short* __restrict__ Wo,
    const float* __restrict__ bias, float* __restrict__ Out)
{
    __shared__ short As[64 * 64];
    __shared__ short Bs[64 * 64];

    const int tid  = threadIdx.x;
    const int lane = tid & 63, w = tid >> 6;
    const int wr = w >> 1, wc = w & 1;
    const int l16 = lane & 15, g = lane >> 4;
    const int m0 = blockIdx.x * 64, n0 = blockIdx.y * 64;

    const short* Ag[2]; const short* Bg[2]; int ldsOff[2];
    #pragma unroll
    for (int f = 0; f < 2; ++f) {
        int c = tid + 256 * f;
        int row = c >> 3, col8 = c & 7;
        int scolw = ((col8 ^ (row & 7)) << 3);
        Ag[f] = Ctx + (size_t)(m0 + row) * Dn + scolw;
        Bg[f] = Wo  + (size_t)(n0 + row) * Dn + scolw;
        ldsOff[f] = (w * 64 + 256 * f) * 8;
    }

    f32x4 acc[2][2];
    #pragma unroll
    for (int i = 0; i < 2; ++i)
        #pragma unroll
        for (int j = 0; j < 2; ++j)
            acc[i][j] = (f32x4){0.f, 0.f, 0.f, 0.f};

    for (int ks = 0; ks < 8; ++ks) {
        #pragma unroll
        for (int f = 0; f < 2; ++f) {
            gl_lds16(Ag[f], &As[ldsOff[f]]);
            gl_lds16(Bg[f], &Bs[ldsOff[f]]);
            Ag[f] += 64; Bg[f] += 64;
        }
        __syncthreads();

        bf16x8 bfv[2][2];
        #pragma unroll
        for (int j = 0; j < 2; ++j) {
            int row = wc * 32 + j * 16 + l16;
            int sw = (row & 7) << 3;
            bfv[j][0] = *(const bf16x8*)&Bs[row * 64 + ((g * 8) ^ sw)];
            bfv[j][1] = *(const bf16x8*)&Bs[row * 64 + ((32 + g * 8) ^ sw)];
        }
        #pragma unroll
        for (int i = 0; i < 2; ++i) {
            int row = wr * 32 + i * 16 + l16;
            int sw = (row & 7) << 3;
            bf16x8 a0 = *(const bf16x8*)&As[row * 64 + ((g * 8) ^ sw)];
            bf16x8 a1 = *(const bf16x8*)&As[row * 64 + ((32 + g * 8) ^ sw)];
            #pragma unroll
            for (int j = 0; j < 2; ++j) {
                acc[i][j] = __builtin_amdgcn_mfma_f32_16x16x32_bf16(a0, bfv[j][0], acc[i][j], 0, 0, 0);
                acc[i][j] = __builtin_amdgcn_mfma_f32_16x16x32_bf16(a1, bfv[j][1], acc[i][j], 0, 0, 0);
            }
        }
        __syncthreads();
    }

    #pragma unroll
    for (int i = 0; i < 2; ++i) {
        #pragma unroll
        for (int j = 0; j < 2; ++j) {
            int n = n0 + wc * 32 + j * 16 + l16;
            float bval = bias[n];
            #pragma unroll
            for (int r = 0; r < 4; ++r) {
                int m = m0 + wr * 32 + i * 16 + g * 4 + r;
                Out[(size_t)m * Dn + n] = acc[i][j][r] + bval;
            }
        }
    }
}

// ---------------------------------------------------------------------------
// Flash attention (R15, unchanged): 16x16x32 bf16 MFMA, swapped QK^T, O^T,
// no-max softmax, MFMA row sums, kc-permuted K (P in registers), DMA staging,
// XCD grid swizzle, MF=2 + in-block KV-split, linear merge.
// ---------------------------------------------------------------------------
__global__ __launch_bounds__(256, 3) void attn_mfma(
    const short* __restrict__ Qh, const short* __restrict__ Kh, const short* __restrict__ Vt,
    const float* __restrict__ maskF, short* __restrict__ Ctx)
{
    __shared__ short smem[16384];

    const int tid  = threadIdx.x;
    const int lane = tid & 63, w = tid >> 6;
    const int l16 = lane & 15, g = lane >> 4;
    const int qt = w & 1, hf = w >> 1;

    const int bid = blockIdx.x;
    const int id  = (bid & 7) * 128 + (bid >> 3);
    const int qb  = id & 31;
    const int bh  = id >> 5;
    const int bb  = bh >> 3, hd = bh & 7;
    const int q0  = qb * 64;
    constexpr int NT = 32;

    const short* Qp = Qh + (size_t)bh * Ln * DKn;
    const short* Kp = Kh + (size_t)bh * Ln * DKn;
    const short* Vp = Vt + (size_t)bh * DKn * Ln;
    const float* mp = maskF + bb * Ln + hf * 1024;

    bf16x8 qf[2][2];
    #pragma unroll
    for (int mf = 0; mf < 2; ++mf)
        #pragma unroll
        for (int c = 0; c < 2; ++c)
            qf[mf][c] = *(const bf16x8*)&Qp[(size_t)(q0 + qt * 32 + mf * 16 + l16) * DKn + c * 32 + g * 8];

    constexpr short BF1 = (short)0x3F80;
    const bf16x8 ones = {BF1, BF1, BF1, BF1, BF1, BF1, BF1, BF1};

    const short* kg[2]; const short* vg[2]; int sbk[2];
    #pragma unroll
    for (int j = 0; j < 2; ++j) {
        int sb = qt * 2 + j;
        sbk[j] = sb * 512;
        int p  = sb * 8 + (lane >> 3);
        int kc = ((p & 0x0C) << 1) | ((p & 0x10) >> 2) | (p & 3);
        int scol = ((lane & 7) ^ (p & 7)) << 3;
        kg[j] = Kp + (size_t)(hf * 1024 + kc) * DKn + scol;
        int vrow = sb * 16 + (lane >> 2);
        int scolv = (((lane & 3) ^ (vrow & 3)) << 3);
        vg[j] = Vp + (size_t)vrow * Ln + hf * 1024 + scolv;
    }

    int kofs[2][2];
    #pragma unroll
    for (int kt = 0; kt < 2; ++kt) {
        int row = kt * 16 + l16;
        kofs[kt][0] = row * 64 + ((g * 8) ^ ((row & 7) << 3));
        kofs[kt][1] = row * 64 + ((32 + g * 8) ^ ((row & 7) << 3));
    }
    int vofs[4];
    #pragma unroll
    for (int d = 0; d < 4; ++d)
        vofs[d] = (d * 16 + l16) * 32 + ((g * 8) ^ ((l16 & 3) << 3));

    f32x4 oacc[2][4];
    #pragma unroll
    for (int mf = 0; mf < 2; ++mf)
        #pragma unroll
        for (int d = 0; d < 4; ++d) oacc[mf][d] = (f32x4){0.f, 0.f, 0.f, 0.f};
    f32x4 lsum[2] = {(f32x4){0.f, 0.f, 0.f, 0.f}, (f32x4){0.f, 0.f, 0.f, 0.f}};

    #pragma unroll
    for (int j = 0; j < 2; ++j) {
        gl_lds16(kg[j], smem + hf * 4096 + sbk[j]);
        gl_lds16(vg[j], smem + 8192 + hf * 4096 + sbk[j]);
    }
    __syncthreads();

    int cb = 0;
    for (int t = 0; t < NT; ++t) {
        if (t < NT - 1) {
            const int ko = (t + 1) * 2048;
            const int vo = (t + 1) * 32;
            short* kd = smem + (hf * 2 + (cb ^ 1)) * 2048;
            short* vd = smem + 8192 + (hf * 2 + (cb ^ 1)) * 2048;
            #pragma unroll
            for (int j = 0; j < 2; ++j) {
                gl_lds16(kg[j] + ko, kd + sbk[j]);
                gl_lds16(vg[j] + vo, vd + sbk[j]);
            }
        }
        const short* Kb = smem + (hf * 2 + cb) * 2048;
        const short* Vb = smem + 8192 + (hf * 2 + cb) * 2048;

        f32x4 mk[2];
        mk[0] = *(const f32x4*)&mp[t * 32 + 8 * g];
        mk[1] = *(const f32x4*)&mp[t * 32 + 8 * g + 4];

        bf16x8 kf[2][2];
        #pragma unroll
        for (int kt = 0; kt < 2; ++kt) {
            kf[kt][0] = *(const bf16x8*)&Kb[kofs[kt][0]];
            kf[kt][1] = *(const bf16x8*)&Kb[kofs[kt][1]];
        }

        f32x4 sv[2][2];
        __builtin_amdgcn_s_setprio(1);
        #pragma unroll
        for (int mf = 0; mf < 2; ++mf)
            #pragma unroll
            for (int kt = 0; kt < 2; ++kt) {
                f32x4 z = __builtin_amdgcn_mfma_f32_16x16x32_bf16(kf[kt][0], qf[mf][0], mk[kt], 0, 0, 0);
                z = __builtin_amdgcn_mfma_f32_16x16x32_bf16(kf[kt][1], qf[mf][1], z, 0, 0, 0);
                sv[mf][kt] = z;
            }
        __builtin_amdgcn_s_setprio(0);

        bf16x8 pf[2];
        #pragma unroll
        for (int mf = 0; mf < 2; ++mf) {
            float e0 = exp2f(sv[mf][0][0]), e1 = exp2f(sv[mf][0][1]);
            float e2 = exp2f(sv[mf][0][2]), e3 = exp2f(sv[mf][0][3]);
            float e4 = exp2f(sv[mf][1][0]), e5 = exp2f(sv[mf][1][1]);
            float e6 = exp2f(sv[mf][1][2]), e7 = exp2f(sv[mf][1][3]);
            union { unsigned u[4]; bf16x8 v; } pu;
            pu.u[0] = cvt_pk_bf16(e0, e1);
            pu.u[1] = cvt_pk_bf16(e2, e3);
            pu.u[2] = cvt_pk_bf16(e4, e5);
            pu.u[3] = cvt_pk_bf16(e6, e7);
            pf[mf] = pu.v;
        }

        bf16x8 vf[4];
        #pragma unroll
        for (int d = 0; d < 4; ++d)
            vf[d] = *(const bf16x8*)&Vb[vofs[d]];

        __builtin_amdgcn_s_setprio(1);
        #pragma unroll
        for (int mf = 0; mf < 2; ++mf) {
            lsum[mf] = __builtin_amdgcn_mfma_f32_16x16x32_bf16(ones, pf[mf], lsum[mf], 0, 0, 0);
            #pragma unroll
            for (int d = 0; d < 4; ++d)
                oacc[mf][d] = __builtin_amdgcn_mfma_f32_16x16x32_bf16(vf[d], pf[mf], oacc[mf][d], 0, 0, 0);
        }
        __builtin_amdgcn_s_setprio(0);

        __syncthreads();
        cb ^= 1;
    }

    float* M = (float*)smem;
    if (hf == 1) {
        #pragma unroll
        for (int mf = 0; mf < 2; ++mf) {
            int ql = qt * 32 + mf * 16 + l16;
            #pragma unroll
            for (int d = 0; d < 4; ++d)
                *(f32x4*)&M[ql * 68 + d * 16 + g * 4] = oacc[mf][d];
            if (g == 0) M[ql * 68 + 64] = lsum[mf][0];
        }
    }
    __syncthreads();
    if (hf == 0) {
        #pragma unroll
        for (int mf = 0; mf < 2; ++mf) {
            int ql = qt * 32 + mf * 16 + l16;
            float lt = lsum[mf][0] + M[ql * 68 + 64];
            float inv = 1.0f / lt;
            size_t mrow = (size_t)bb * Ln + q0 + ql;
            #pragma unroll
            for (int d = 0; d < 4; ++d) {
                f32x4 ob = *(const f32x4*)&M[ql * 68 + d * 16 + g * 4];
                float o0 = (oacc[mf][d][0] + ob[0]) * inv;
                float o1 = (oacc[mf][d][1] + ob[1]) * inv;
                float o2 = (oacc[mf][d][2] + ob[2]) * inv;
                float o3 = (oacc[mf][d][3] + ob[3]) * inv;
                uint2 pr = {cvt_pk_bf16(o0, o1), cvt_pk_bf16(o2, o3)};
                *(uint2*)&Ctx[mrow * Dn + hd * 64 + d * 16 + g * 4] = pr;
            }
        }
    }
}

// ---------------------------------------------------------------------------
// Fallback kernels (fp32-input projections) for small workspaces.
// ---------------------------------------------------------------------------
__global__ __launch_bounds__(256) void qkv_proj_mfma(
    const float* __restrict__ q, const float* __restrict__ k, const float* __restrict__ v,
    const float* __restrict__ wq, const float* __restrict__ wk, const float* __restrict__ wv,
    const float* __restrict__ bq, const float* __restrict__ bk, const float* __restrict__ bv,
    short* __restrict__ Qh, short* __restrict__ Kh, short* __restrict__ Vt)
{
    const int p = blockIdx.z;
    const float* X    = (p == 0) ? q  : (p == 1) ? k  : v;
    const float* W    = (p == 0) ? wq : (p == 1) ? wk : wv;
    const float* bias = (p == 0) ? bq : (p == 1) ? bk : bv;
    short*       O    = (p == 0) ? Qh : (p == 1) ? Kh : Vt;
    const float scl   = (p == 0) ? QSCALE : 1.0f;

    __shared__ short As[128 * 72];
    __shared__ short Bs[128 * 72];

    const int tid  = threadIdx.x;
    const int lane = tid & 63, w = tid >> 6;
    const int wr = w >> 1, wc = w & 1;
    const int l16 = lane & 15, g = lane >> 4;
    const int m0 = blockIdx.x * 128, n0 = blockIdx.y * 128;

    f32x4 acc[4][4];
    #pragma unroll
    for (int i = 0; i < 4; ++i)
        #pragma unroll
        for (int j = 0; j < 4; ++j)
            acc[i][j] = (f32x4){0.f, 0.f, 0.f, 0.f};

    for (int k0 = 0; k0 < Dn; k0 += 64) {
        #pragma unroll
        for (int f = 0; f < 8; ++f) {
            int lin = tid + 256 * f;
            int row = lin >> 4, c4 = lin & 15;
            float4 xv = *(const float4*)&X[(size_t)(m0 + row) * Dn + k0 + c4 * 4];
            uint2 xp = {cvt_pk_bf16(xv.x, xv.y), cvt_pk_bf16(xv.z, xv.w)};
            *(uint2*)&As[row * 72 + c4 * 4] = xp;
            float4 wv4 = *(const float4*)&W[(size_t)(n0 + row) * Dn + k0 + c4 * 4];
            uint2 wp = {cvt_pk_bf16(wv4.x, wv4.y), cvt_pk_bf16(wv4.z, wv4.w)};
            *(uint2*)&Bs[row * 72 + c4 * 4] = wp;
        }
        __syncthreads();

        bf16x8 af[4][2], bfv[4][2];
        #pragma unroll
        for (int i = 0; i < 4; ++i)
            #pragma unroll
            for (int c = 0; c < 2; ++c)
                af[i][c] = *(const bf16x8*)&As[(wr * 64 + i * 16 + l16) * 72 + c * 32 + g * 8];
        #pragma unroll
        for (int j = 0; j < 4; ++j)
            #pragma unroll
            for (int c = 0; c < 2; ++c)
                bfv[j][c] = *(const bf16x8*)&Bs[(wc * 64 + j * 16 + l16) * 72 + c * 32 + g * 8];

        #pragma unroll
        for (int i = 0; i < 4; ++i)
            #pragma unroll
            for (int j = 0; j < 4; ++j) {
                acc[i][j] = __builtin_amdgcn_mfma_f32_16x16x32_bf16(af[i][0], bfv[j][0], acc[i][j], 0, 0, 0);
                acc[i][j] = __builtin_amdgcn_mfma_f32_16x16x32_bf16(af[i][1], bfv[j][1], acc[i][j], 0, 0, 0);
            }
        __syncthreads();
    }

    const int bb = m0 >> 11;
    #pragma unroll
    for (int i = 0; i < 4; ++i) {
        #pragma unroll
        for (int j = 0; j < 4; ++j) {
            int n  = n0 + wc * 64 + j * 16 + l16;
            int h  = n >> 6, dk = n & 63;
            float bval = bias[n];
            #pragma unroll
            for (int r = 0; r < 4; ++r) {
                int m  = m0 + wr * 64 + i * 16 + g * 4 + r;
                int lq = m & (Ln - 1);
                short val = f2bf((acc[i][j][r] + bval) * scl);
                if (p < 2)
                    O[(((size_t)bb * Hn + h) * Ln + lq) * DKn + dk] = val;
                else
                    O[(((size_t)bb * Hn + h) * DKn + dk) * Ln + lq] = val;
            }
        }
    }
}

__global__ __launch_bounds__(256) void out_proj_mfma(
    const short* __restrict__ Ctx, const float* __restrict__ W,
    const float* __restrict__ bias, float* __restrict__ Out)
{
    __shared__ short As[128 * 72];
    __shared__ short Bs[128 * 72];

    const int tid  = threadIdx.x;
    const int lane = tid & 63, w = tid >> 6;
    const int wr = w >> 1, wc = w & 1;
    const int l16 = lane & 15, g = lane >> 4;
    const int m0 = blockIdx.x * 128, n0 = blockIdx.y * 128;

    f32x4 acc[4][4];
    #pragma unroll
    for (int i = 0; i < 4; ++i)
        #pragma unroll
        for (int j = 0; j < 4; ++j)
            acc[i][j] = (f32x4){0.f, 0.f, 0.f, 0.f};

    for (int k0 = 0; k0 < Dn; k0 += 64) {
        #pragma unroll
        for (int f = 0; f < 4; ++f) {
            int lin = tid + 256 * f;
            int row = lin >> 3, c8 = lin & 7;
            bf16x8 av = *(const bf16x8*)&Ctx[(size_t)(m0 + row) * Dn + k0 + c8 * 8];
            *(bf16x8*)&As[row * 72 + c8 * 8] = av;
        }
        #pragma unroll
        for (int f = 0; f < 8; ++f) {
            int lin = tid + 256 * f;
            int row = lin >> 4, c4 = lin & 15;
            float4 wv4 = *(const float4*)&W[(size_t)(n0 + row) * Dn + k0 + c4 * 4];
            uint2 wp = {cvt_pk_bf16(wv4.x, wv4.y), cvt_pk_bf16(wv4.z, wv4.w)};
            *(uint2*)&Bs[row * 72 + c4 * 4] = wp;
        }
        __syncthreads();

        bf16x8 af[4][2], bfv[4][2];
        #pragma unroll
        for (int i = 0; i < 4; ++i)
            #pragma unroll
            for (int c = 0; c < 2; ++c)
                af[i][c] = *(const bf16x8*)&As[(wr * 64 + i * 16 + l16) * 72 + c * 32 + g * 8];
        #pragma unroll
        for (int j = 0; j < 4; ++j)
            #pragma unroll
            for (int c = 0; c < 2; ++c)
                bfv[j][c] = *(const bf16x8*)&Bs[(wc * 64 + j * 16 + l16) * 72 + c * 32 + g * 8];

        #pragma unroll
        for (int i = 0; i < 4; ++i)
            #pragma unroll
            for (int j = 0; j < 4; ++j) {
                acc[i][j] = __builtin_amdgcn_mfma_f32_16x16x32_bf16(af[i][0], bfv[j][0], acc[i][j], 0, 0, 0);
                acc[i][j] = __builtin_amdgcn_mfma_f32_16x16x32_bf16(af[i][1], bfv[j][1], acc[i][j], 0, 0, 0);
            }
        __syncthreads();
    }

    #pragma unroll
    for (int i = 0; i < 4; ++i) {
        #pragma unroll
        for (int j = 0; j < 4; ++j) {
            int n = n0 + wc * 64 + j * 16 + l16;
            float bval = bias[n];
            #pragma unroll
            for (int r = 0; r < 4; ++r) {
                int m = m0 + wr * 64 + i * 16 + g * 4 + r;
                Out[(size_t)m * Dn + n] = acc[i][j][r] + bval;
            }
        }
    }
}

// ---------------------------------------------------------------------------
extern "C" void kernel_launch(void* const* d_in, const int* in_sizes, int n_in,
                              void* d_out, int out_size, void* d_ws, size_t ws_size,
                              hipStream_t stream)
{
    (void)in_sizes; (void)n_in; (void)out_size;
    const float* q    = (const float*)d_in[0];
    const float* k    = (const float*)d_in[1];
    const float* v    = (const float*)d_in[2];
    const int*   mks  = (const int*)  d_in[3];
    const float* wq_w = (const float*)d_in[4];
    const float* wq_b = (const float*)d_in[5];
    const float* wk_w = (const float*)d_in[6];
    const float* wk_b = (const float*)d_in[7];
    const float* wv_w = (const float*)d_in[8];
    const float* wv_b = (const float*)d_in[9];
    const float* wo_w = (const float*)d_in[10];
    const float* wo_b = (const float*)d_in[11];
    float* out = (float*)d_out;

    short* ws = (short*)d_ws;
    const size_t needed = (4 * HE + 4 * WN + 2 * (size_t)Bn * Ln) * 2;   // ~36 MiB

    if (ws_size >= needed) {
        short* Qh   = ws;
        short* Kh   = ws + HE;
        short* Vt   = ws + 2 * HE;
        short* Ctx  = ws + 3 * HE;
        short* Wb   = ws + 4 * HE;           // 4*WN
        float* maskF = (float*)(ws + 4 * HE + 4 * WN);

        const int prepBlocks = (int)((WN + (size_t)Bn * Ln + 255) / 256);
        prep_wm<<<dim3(prepBlocks), 256, 0, stream>>>(
            wq_w, wk_w, wv_w, wo_w, mks, Wb, maskF);

        qkv_proj_f32<<<dim3(128, 4, 3), 256, 0, stream>>>(
            q, k, v, Wb, wq_b, wk_b, wv_b, Qh, Kh, Vt);

        attn_mfma<<<dim3(1024), 256, 0, stream>>>(Qh, Kh, Vt, maskF, Ctx);

        out_proj_bf16<<<dim3(128, 8), 256, 0, stream>>>(Ctx, Wb + 3 * WN, wo_b, out);
    } else {
        short* Qh  = ws;
        short* Kh  = ws + HE;
        short* Vt  = ws + 2 * HE;
        short* Ctx = ws + 3 * HE;
        float* maskF = (float*)(ws + 4 * HE);

        mask_prep<<<dim3(32), 256, 0, stream>>>(mks, maskF);
        qkv_proj_mfma<<<dim3(Mtot / 128, Dn / 128, 3), 256, 0, stream>>>(
            q, k, v, wq_w, wk_w, wv_w, wq_b, wk_b, wv_b, Qh, Kh, Vt);
        attn_mfma<<<dim3(1024), 256, 0, stream>>>(Qh, Kh, Vt, maskF, Ctx);
        out_proj_mfma<<<dim3(Mtot / 128, Dn / 128), 256, 0, stream>>>(Ctx, wo_w, wo_b, out);
    }
}

// Round 18
// 108.506 us; speedup vs baseline: 1.0507x; 1.0045x over previous
//
#include <hip/hip_runtime.h>
#include <hip/hip_bf16.h>
#include <cstddef>

typedef __attribute__((ext_vector_type(8)))  short bf16x8;
typedef __attribute__((ext_vector_type(4)))  float f32x4;

constexpr int Bn = 4, Ln = 2048, Dn = 512, Hn = 8, DKn = 64, Mtot = 8192;
constexpr float QSCALE = 0.125f * 1.44269504088896341f;   // 1/sqrt(DK) * log2(e)
constexpr size_t HE = (size_t)Bn * Hn * Ln * DKn;          // 4,194,304
constexpr size_t WN = (size_t)Dn * Dn;                     // 262,144

__device__ inline unsigned cvt_pk_bf16(float lo, float hi) {
    unsigned r;
    asm("v_cvt_pk_bf16_f32 %0, %1, %2" : "=v"(r) : "v"(lo), "v"(hi));
    return r;
}
__device__ inline short f2bf(float x) {
    union { float f; unsigned u; } v; v.f = x;
    unsigned r = v.u + 0x7fffu + ((v.u >> 16) & 1u);
    return (short)(r >> 16);
}
__device__ inline void gl_lds16(const short* g, short* l) {
    __builtin_amdgcn_global_load_lds(
        (const __attribute__((address_space(1))) void*)g,
        (__attribute__((address_space(3))) void*)l, 16, 0, 0);
}
__device__ inline void gl_lds16f(const float* g, float* l) {
    __builtin_amdgcn_global_load_lds(
        (const __attribute__((address_space(1))) void*)g,
        (__attribute__((address_space(3))) void*)l, 16, 0, 0);
}

// ---------------------------------------------------------------------------
// Slim prep: cast 4 weights -> bf16, mask -> -1e30/0.  grid 1056 x 256.
// ---------------------------------------------------------------------------
__global__ __launch_bounds__(256) void prep_wm(
    const float* __restrict__ wq, const float* __restrict__ wk,
    const float* __restrict__ wv, const float* __restrict__ wo,
    const int* __restrict__ masks,
    short* __restrict__ Wb, float* __restrict__ maskF)
{
    size_t gid = (size_t)blockIdx.x * 256 + threadIdx.x;
    if (gid < WN) {
        int which = (int)(gid >> 16);
        const float* src = (which == 0) ? wq : (which == 1) ? wk : (which == 2) ? wv : wo;
        size_t i4 = gid & 65535;
        float4 xv = *(const float4*)&src[i4 * 4];
        uint2 p = {cvt_pk_bf16(xv.x, xv.y), cvt_pk_bf16(xv.z, xv.w)};
        *(uint2*)&Wb[(size_t)which * WN + i4 * 4] = p;
    } else {
        size_t mi = gid - WN;
        if (mi < (size_t)Bn * Ln) maskF[mi] = (masks[mi] == 0) ? -1e30f : 0.f;
    }
}

__global__ __launch_bounds__(256) void mask_prep(
    const int* __restrict__ masks, float* __restrict__ maskF)
{
    int i = blockIdx.x * 256 + threadIdx.x;
    if (i < Bn * Ln) maskF[i] = (masks[i] == 0) ? -1e30f : 0.f;
}

// ---------------------------------------------------------------------------
// QKV projection (R17): BM=64 x BN=128, A fp32 DMA + convert-at-read,
// B bf16 DMA.  LDS 32 KB.  grid (128, 4, 3) x 256, 8 K-steps.
// ---------------------------------------------------------------------------
__global__ __launch_bounds__(256) void qkv_proj_f32(
    const float* __restrict__ q, const float* __restrict__ k, const float* __restrict__ v,
    const short* __restrict__ Wb,
    const float* __restrict__ bq, const float* __restrict__ bk, const float* __restrict__ bv,
    short* __restrict__ Qh, short* __restrict__ Kh, short* __restrict__ Vt)
{
    const int p = blockIdx.z;
    const float* X    = (p == 0) ? q : (p == 1) ? k : v;
    const short* W    = Wb + (size_t)p * WN;
    const float* bias = (p == 0) ? bq : (p == 1) ? bk : bv;
    short*       O    = (p == 0) ? Qh : (p == 1) ? Kh : Vt;
    const float scl   = (p == 0) ? QSCALE : 1.0f;

    __shared__ float Af[64 * 64];    // 16 KB
    __shared__ short Bs[128 * 64];   // 16 KB

    const int tid  = threadIdx.x;
    const int lane = tid & 63, w = tid >> 6;
    const int wr = w >> 1, wc = w & 1;
    const int l16 = lane & 15, g = lane >> 4;
    const int m0 = blockIdx.x * 64, n0 = blockIdx.y * 128;

    const int rA = tid >> 4, col4 = tid & 15;
    const int scolA = (col4 * 4) ^ (8 * (rA & 7));
    const float* Ag = X + (size_t)(m0 + rA) * Dn + scolA;
    const int rB = tid >> 3, c8 = tid & 7;
    const int scolB = ((c8 ^ (rB & 7)) << 3);
    const short* Bg = W + (size_t)(n0 + rB) * Dn + scolB;

    f32x4 acc[2][4];
    #pragma unroll
    for (int i = 0; i < 2; ++i)
        #pragma unroll
        for (int j = 0; j < 4; ++j)
            acc[i][j] = (f32x4){0.f, 0.f, 0.f, 0.f};

    for (int ks = 0; ks < 8; ++ks) {
        #pragma unroll
        for (int f = 0; f < 4; ++f)
            gl_lds16f(Ag + (size_t)f * 16 * Dn, &Af[(w * 64 + 256 * f) * 4]);
        #pragma unroll
        for (int f = 0; f < 4; ++f)
            gl_lds16(Bg + (size_t)f * 32 * Dn, &Bs[(w * 64 + 256 * f) * 8]);
        Ag += 64; Bg += 64;
        __syncthreads();

        bf16x8 bfv[4][2];
        #pragma unroll
        for (int j = 0; j < 4; ++j) {
            int row = wc * 64 + j * 16 + l16;
            int sw = (row & 7) << 3;
            bfv[j][0] = *(const bf16x8*)&Bs[row * 64 + ((g * 8) ^ sw)];
            bfv[j][1] = *(const bf16x8*)&Bs[row * 64 + ((32 + g * 8) ^ sw)];
        }
        #pragma unroll
        for (int i = 0; i < 2; ++i) {
            int row = wr * 32 + i * 16 + l16;
            int m8 = 8 * (row & 7);
            bf16x8 a[2];
            #pragma unroll
            for (int c = 0; c < 2; ++c) {
                int base = row * 64 + ((g * 8 + c * 32) ^ m8);
                f32x4 x0 = *(const f32x4*)&Af[base];
                f32x4 x1 = *(const f32x4*)&Af[base + 4];
                union { unsigned u[4]; bf16x8 v; } pu;
                pu.u[0] = cvt_pk_bf16(x0[0], x0[1]);
                pu.u[1] = cvt_pk_bf16(x0[2], x0[3]);
                pu.u[2] = cvt_pk_bf16(x1[0], x1[1]);
                pu.u[3] = cvt_pk_bf16(x1[2], x1[3]);
                a[c] = pu.v;
            }
            #pragma unroll
            for (int j = 0; j < 4; ++j) {
                acc[i][j] = __builtin_amdgcn_mfma_f32_16x16x32_bf16(a[0], bfv[j][0], acc[i][j], 0, 0, 0);
                acc[i][j] = __builtin_amdgcn_mfma_f32_16x16x32_bf16(a[1], bfv[j][1], acc[i][j], 0, 0, 0);
            }
        }
        __syncthreads();
    }

    const int bb = m0 >> 11;
    #pragma unroll
    for (int i = 0; i < 2; ++i) {
        #pragma unroll
        for (int j = 0; j < 4; ++j) {
            int n  = n0 + wc * 64 + j * 16 + l16;
            int h  = n >> 6, dk = n & 63;
            float bval = bias[n];
            #pragma unroll
            for (int r = 0; r < 4; ++r) {
                int m  = m0 + wr * 32 + i * 16 + g * 4 + r;
                int lq = m & (Ln - 1);
                short val = f2bf((acc[i][j][r] + bval) * scl);
                if (p < 2)
                    O[(((size_t)bb * Hn + h) * Ln + lq) * DKn + dk] = val;
                else
                    O[(((size_t)bb * Hn + h) * DKn + dk) * Ln + lq] = val;
            }
        }
    }
}

// ---------------------------------------------------------------------------
// Output projection v18: 64x64 tile, DOUBLE-BUFFERED DMA (one barrier per
// K-step; DMA latency hides under MFMA).  LDS 32 KB.  grid (128, 8) x 256.
// ---------------------------------------------------------------------------
__global__ __launch_bounds__(256) void out_proj_bf16(
    const short* __restrict__ Ctx, const short* __restrict__ Wo,
    const float* __restrict__ bias, float* __restrict__ Out)
{
    __shared__ short As[2][64 * 64];
    __shared__ short Bs[2][64 * 64];

    const int tid  = threadIdx.x;
    const int lane = tid & 63, w = tid >> 6;
    const int wr = w >> 1, wc = w & 1;
    const int l16 = lane & 15, g = lane >> 4;
    const int m0 = blockIdx.x * 64, n0 = blockIdx.y * 64;

    const short* Ag[2]; const short* Bg[2]; int ldsOff[2];
    #pragma unroll
    for (int f = 0; f < 2; ++f) {
        int c = tid + 256 * f;
        int row = c >> 3, col8 = c & 7;
        int scolw = ((col8 ^ (row & 7)) << 3);
        Ag[f] = Ctx + (size_t)(m0 + row) * Dn + scolw;
        Bg[f] = Wo  + (size_t)(n0 + row) * Dn + scolw;
        ldsOff[f] = (w * 64 + 256 * f) * 8;
    }

    f32x4 acc[2][2];
    #pragma unroll
    for (int i = 0; i < 2; ++i)
        #pragma unroll
        for (int j = 0; j < 2; ++j)
            acc[i][j] = (f32x4){0.f, 0.f, 0.f, 0.f};

    // prologue: stage K-step 0 into buffer 0
    #pragma unroll
    for (int f = 0; f < 2; ++f) {
        gl_lds16(Ag[f], &As[0][ldsOff[f]]);
        gl_lds16(Bg[f], &Bs[0][ldsOff[f]]);
        Ag[f] += 64; Bg[f] += 64;
    }
    __syncthreads();

    int cb = 0;
    for (int ks = 0; ks < 8; ++ks) {
        if (ks < 7) {
            #pragma unroll
            for (int f = 0; f < 2; ++f) {
                gl_lds16(Ag[f], &As[cb ^ 1][ldsOff[f]]);
                gl_lds16(Bg[f], &Bs[cb ^ 1][ldsOff[f]]);
                Ag[f] += 64; Bg[f] += 64;
            }
        }

        bf16x8 bfv[2][2];
        #pragma unroll
        for (int j = 0; j < 2; ++j) {
            int row = wc * 32 + j * 16 + l16;
            int sw = (row & 7) << 3;
            bfv[j][0] = *(const bf16x8*)&Bs[cb][row * 64 + ((g * 8) ^ sw)];
            bfv[j][1] = *(const bf16x8*)&Bs[cb][row * 64 + ((32 + g * 8) ^ sw)];
        }
        #pragma unroll
        for (int i = 0; i < 2; ++i) {
            int row = wr * 32 + i * 16 + l16;
            int sw = (row & 7) << 3;
            bf16x8 a0 = *(const bf16x8*)&As[cb][row * 64 + ((g * 8) ^ sw)];
            bf16x8 a1 = *(const bf16x8*)&As[cb][row * 64 + ((32 + g * 8) ^ sw)];
            #pragma unroll
            for (int j = 0; j < 2; ++j) {
                acc[i][j] = __builtin_amdgcn_mfma_f32_16x16x32_bf16(a0, bfv[j][0], acc[i][j], 0, 0, 0);
                acc[i][j] = __builtin_amdgcn_mfma_f32_16x16x32_bf16(a1, bfv[j][1], acc[i][j], 0, 0, 0);
            }
        }
        __syncthreads();
        cb ^= 1;
    }

    #pragma unroll
    for (int i = 0; i < 2; ++i) {
        #pragma unroll
        for (int j = 0; j < 2; ++j) {
            int n = n0 + wc * 32 + j * 16 + l16;
            float bval = bias[n];
            #pragma unroll
            for (int r = 0; r < 4; ++r) {
                int m = m0 + wr * 32 + i * 16 + g * 4 + r;
                Out[(size_t)m * Dn + n] = acc[i][j][r] + bval;
            }
        }
    }
}

// ---------------------------------------------------------------------------
// Flash attention (R17 + mask register-prefetch): 16x16x32 bf16 MFMA,
// swapped QK^T, O^T, no-max softmax, MFMA row sums, kc-permuted K (P in
// registers), DMA staging, XCD grid swizzle, MF=2 + KV-split, linear merge.
// ---------------------------------------------------------------------------
__global__ __launch_bounds__(256, 3) void attn_mfma(
    const short* __restrict__ Qh, const short* __restrict__ Kh, const short* __restrict__ Vt,
    const float* __restrict__ maskF, short* __restrict__ Ctx)
{
    __shared__ short smem[16384];

    const int tid  = threadIdx.x;
    const int lane = tid & 63, w = tid >> 6;
    const int l16 = lane & 15, g = lane >> 4;
    const int qt = w & 1, hf = w >> 1;

    const int bid = blockIdx.x;
    const int id  = (bid & 7) * 128 + (bid >> 3);
    const int qb  = id & 31;
    const int bh  = id >> 5;
    const int bb  = bh >> 3, hd = bh & 7;
    const int q0  = qb * 64;
    constexpr int NT = 32;

    const short* Qp = Qh + (size_t)bh * Ln * DKn;
    const short* Kp = Kh + (size_t)bh * Ln * DKn;
    const short* Vp = Vt + (size_t)bh * DKn * Ln;
    const float* mp = maskF + bb * Ln + hf * 1024;

    bf16x8 qf[2][2];
    #pragma unroll
    for (int mf = 0; mf < 2; ++mf)
        #pragma unroll
        for (int c = 0; c < 2; ++c)
            qf[mf][c] = *(const bf16x8*)&Qp[(size_t)(q0 + qt * 32 + mf * 16 + l16) * DKn + c * 32 + g * 8];

    constexpr short BF1 = (short)0x3F80;
    const bf16x8 ones = {BF1, BF1, BF1, BF1, BF1, BF1, BF1, BF1};

    const short* kg[2]; const short* vg[2]; int sbk[2];
    #pragma unroll
    for (int j = 0; j < 2; ++j) {
        int sb = qt * 2 + j;
        sbk[j] = sb * 512;
        int p  = sb * 8 + (lane >> 3);
        int kc = ((p & 0x0C) << 1) | ((p & 0x10) >> 2) | (p & 3);
        int scol = ((lane & 7) ^ (p & 7)) << 3;
        kg[j] = Kp + (size_t)(hf * 1024 + kc) * DKn + scol;
        int vrow = sb * 16 + (lane >> 2);
        int scolv = (((lane & 3) ^ (vrow & 3)) << 3);
        vg[j] = Vp + (size_t)vrow * Ln + hf * 1024 + scolv;
    }

    int kofs[2][2];
    #pragma unroll
    for (int kt = 0; kt < 2; ++kt) {
        int row = kt * 16 + l16;
        kofs[kt][0] = row * 64 + ((g * 8) ^ ((row & 7) << 3));
        kofs[kt][1] = row * 64 + ((32 + g * 8) ^ ((row & 7) << 3));
    }
    int vofs[4];
    #pragma unroll
    for (int d = 0; d < 4; ++d)
        vofs[d] = (d * 16 + l16) * 32 + ((g * 8) ^ ((l16 & 3) << 3));

    f32x4 oacc[2][4];
    #pragma unroll
    for (int mf = 0; mf < 2; ++mf)
        #pragma unroll
        for (int d = 0; d < 4; ++d) oacc[mf][d] = (f32x4){0.f, 0.f, 0.f, 0.f};
    f32x4 lsum[2] = {(f32x4){0.f, 0.f, 0.f, 0.f}, (f32x4){0.f, 0.f, 0.f, 0.f}};

    #pragma unroll
    for (int j = 0; j < 2; ++j) {
        gl_lds16(kg[j], smem + hf * 4096 + sbk[j]);
        gl_lds16(vg[j], smem + 8192 + hf * 4096 + sbk[j]);
    }
    // mask prefetch for tile 0
    f32x4 mkA0 = *(const f32x4*)&mp[8 * g];
    f32x4 mkA1 = *(const f32x4*)&mp[8 * g + 4];
    __syncthreads();

    int cb = 0;
    for (int t = 0; t < NT; ++t) {
        if (t < NT - 1) {
            const int ko = (t + 1) * 2048;
            const int vo = (t + 1) * 32;
            short* kd = smem + (hf * 2 + (cb ^ 1)) * 2048;
            short* vd = smem + 8192 + (hf * 2 + (cb ^ 1)) * 2048;
            #pragma unroll
            for (int j = 0; j < 2; ++j) {
                gl_lds16(kg[j] + ko, kd + sbk[j]);
                gl_lds16(vg[j] + vo, vd + sbk[j]);
            }
        }
        const short* Kb = smem + (hf * 2 + cb) * 2048;
        const short* Vb = smem + 8192 + (hf * 2 + cb) * 2048;

        // current tile's mask (prefetched); prefetch next tile's
        f32x4 mk[2] = {mkA0, mkA1};
        if (t < NT - 1) {
            mkA0 = *(const f32x4*)&mp[(t + 1) * 32 + 8 * g];
            mkA1 = *(const f32x4*)&mp[(t + 1) * 32 + 8 * g + 4];
        }

        bf16x8 kf[2][2];
        #pragma unroll
        for (int kt = 0; kt < 2; ++kt) {
            kf[kt][0] = *(const bf16x8*)&Kb[kofs[kt][0]];
            kf[kt][1] = *(const bf16x8*)&Kb[kofs[kt][1]];
        }

        f32x4 sv[2][2];
        __builtin_amdgcn_s_setprio(1);
        #pragma unroll
        for (int mf = 0; mf < 2; ++mf)
            #pragma unroll
            for (int kt = 0; kt < 2; ++kt) {
                f32x4 z = __builtin_amdgcn_mfma_f32_16x16x32_bf16(kf[kt][0], qf[mf][0], mk[kt], 0, 0, 0);
                z = __builtin_amdgcn_mfma_f32_16x16x32_bf16(kf[kt][1], qf[mf][1], z, 0, 0, 0);
                sv[mf][kt] = z;
            }
        __builtin_amdgcn_s_setprio(0);

        bf16x8 pf[2];
        #pragma unroll
        for (int mf = 0; mf < 2; ++mf) {
            float e0 = exp2f(sv[mf][0][0]), e1 = exp2f(sv[mf][0][1]);
            float e2 = exp2f(sv[mf][0][2]), e3 = exp2f(sv[mf][0][3]);
            float e4 = exp2f(sv[mf][1][0]), e5 = exp2f(sv[mf][1][1]);
            float e6 = exp2f(sv[mf][1][2]), e7 = exp2f(sv[mf][1][3]);
            union { unsigned u[4]; bf16x8 v; } pu;
            pu.u[0] = cvt_pk_bf16(e0, e1);
            pu.u[1] = cvt_pk_bf16(e2, e3);
            pu.u[2] = cvt_pk_bf16(e4, e5);
            pu.u[3] = cvt_pk_bf16(e6, e7);
            pf[mf] = pu.v;
        }

        bf16x8 vf[4];
        #pragma unroll
        for (int d = 0; d < 4; ++d)
            vf[d] = *(const bf16x8*)&Vb[vofs[d]];

        __builtin_amdgcn_s_setprio(1);
        #pragma unroll
        for (int mf = 0; mf < 2; ++mf) {
            lsum[mf] = __builtin_amdgcn_mfma_f32_16x16x32_bf16(ones, pf[mf], lsum[mf], 0, 0, 0);
            #pragma unroll
            for (int d = 0; d < 4; ++d)
                oacc[mf][d] = __builtin_amdgcn_mfma_f32_16x16x32_bf16(vf[d], pf[mf], oacc[mf][d], 0, 0, 0);
        }
        __builtin_amdgcn_s_setprio(0);

        __syncthreads();
        cb ^= 1;
    }

    float* M = (float*)smem;
    if (hf == 1) {
        #pragma unroll
        for (int mf = 0; mf < 2; ++mf) {
            int ql = qt * 32 + mf * 16 + l16;
            #pragma unroll
            for (int d = 0; d < 4; ++d)
                *(f32x4*)&M[ql * 68 + d * 16 + g * 4] = oacc[mf][d];
            if (g == 0) M[ql * 68 + 64] = lsum[mf][0];
        }
    }
    __syncthreads();
    if (hf == 0) {
        #pragma unroll
        for (int mf = 0; mf < 2; ++mf) {
            int ql = qt * 32 + mf * 16 + l16;
            float lt = lsum[mf][0] + M[ql * 68 + 64];
            float inv = 1.0f / lt;
            size_t mrow = (size_t)bb * Ln + q0 + ql;
            #pragma unroll
            for (int d = 0; d < 4; ++d) {
                f32x4 ob = *(const f32x4*)&M[ql * 68 + d * 16 + g * 4];
                float o0 = (oacc[mf][d][0] + ob[0]) * inv;
                float o1 = (oacc[mf][d][1] + ob[1]) * inv;
                float o2 = (oacc[mf][d][2] + ob[2]) * inv;
                float o3 = (oacc[mf][d][3] + ob[3]) * inv;
                uint2 pr = {cvt_pk_bf16(o0, o1), cvt_pk_bf16(o2, o3)};
                *(uint2*)&Ctx[mrow * Dn + hd * 64 + d * 16 + g * 4] = pr;
            }
        }
    }
}

// ---------------------------------------------------------------------------
// Fallback kernels (fp32-input projections) for small workspaces.
// ---------------------------------------------------------------------------
__global__ __launch_bounds__(256) void qkv_proj_mfma(
    const float* __restrict__ q, const float* __restrict__ k, const float* __restrict__ v,
    const float* __restrict__ wq, const float* __restrict__ wk, const float* __restrict__ wv,
    const float* __restrict__ bq, const float* __restrict__ bk, const float* __restrict__ bv,
    short* __restrict__ Qh, short* __restrict__ Kh, short* __restrict__ Vt)
{
    const int p = blockIdx.z;
    const float* X    = (p == 0) ? q  : (p == 1) ? k  : v;
    const float* W    = (p == 0) ? wq : (p == 1) ? wk : wv;
    const float* bias = (p == 0) ? bq : (p == 1) ? bk : bv;
    short*       O    = (p == 0) ? Qh : (p == 1) ? Kh : Vt;
    const float scl   = (p == 0) ? QSCALE : 1.0f;

    __shared__ short As[128 * 72];
    __shared__ short Bs[128 * 72];

    const int tid  = threadIdx.x;
    const int lane = tid & 63, w = tid >> 6;
    const int wr = w >> 1, wc = w & 1;
    const int l16 = lane & 15, g = lane >> 4;
    const int m0 = blockIdx.x * 128, n0 = blockIdx.y * 128;

    f32x4 acc[4][4];
    #pragma unroll
    for (int i = 0; i < 4; ++i)
        #pragma unroll
        for (int j = 0; j < 4; ++j)
            acc[i][j] = (f32x4){0.f, 0.f, 0.f, 0.f};

    for (int k0 = 0; k0 < Dn; k0 += 64) {
        #pragma unroll
        for (int f = 0; f < 8; ++f) {
            int lin = tid + 256 * f;
            int row = lin >> 4, c4 = lin & 15;
            float4 xv = *(const float4*)&X[(size_t)(m0 + row) * Dn + k0 + c4 * 4];
            uint2 xp = {cvt_pk_bf16(xv.x, xv.y), cvt_pk_bf16(xv.z, xv.w)};
            *(uint2*)&As[row * 72 + c4 * 4] = xp;
            float4 wv4 = *(const float4*)&W[(size_t)(n0 + row) * Dn + k0 + c4 * 4];
            uint2 wp = {cvt_pk_bf16(wv4.x, wv4.y), cvt_pk_bf16(wv4.z, wv4.w)};
            *(uint2*)&Bs[row * 72 + c4 * 4] = wp;
        }
        __syncthreads();

        bf16x8 af[4][2], bfv[4][2];
        #pragma unroll
        for (int i = 0; i < 4; ++i)
            #pragma unroll
            for (int c = 0; c < 2; ++c)
                af[i][c] = *(const bf16x8*)&As[(wr * 64 + i * 16 + l16) * 72 + c * 32 + g * 8];
        #pragma unroll
        for (int j = 0; j < 4; ++j)
            #pragma unroll
            for (int c = 0; c < 2; ++c)
                bfv[j][c] = *(const bf16x8*)&Bs[(wc * 64 + j * 16 + l16) * 72 + c * 32 + g * 8];

        #pragma unroll
        for (int i = 0; i < 4; ++i)
            #pragma unroll
            for (int j = 0; j < 4; ++j) {
                acc[i][j] = __builtin_amdgcn_mfma_f32_16x16x32_bf16(af[i][0], bfv[j][0], acc[i][j], 0, 0, 0);
                acc[i][j] = __builtin_amdgcn_mfma_f32_16x16x32_bf16(af[i][1], bfv[j][1], acc[i][j], 0, 0, 0);
            }
        __syncthreads();
    }

    const int bb = m0 >> 11;
    #pragma unroll
    for (int i = 0; i < 4; ++i) {
        #pragma unroll
        for (int j = 0; j < 4; ++j) {
            int n  = n0 + wc * 64 + j * 16 + l16;
            int h  = n >> 6, dk = n & 63;
            float bval = bias[n];
            #pragma unroll
            for (int r = 0; r < 4; ++r) {
                int m  = m0 + wr * 64 + i * 16 + g * 4 + r;
                int lq = m & (Ln - 1);
                short val = f2bf((acc[i][j][r] + bval) * scl);
                if (p < 2)
                    O[(((size_t)bb * Hn + h) * Ln + lq) * DKn + dk] = val;
                else
                    O[(((size_t)bb * Hn + h) * DKn + dk) * Ln + lq] = val;
            }
        }
    }
}

__global__ __launch_bounds__(256) void out_proj_mfma(
    const short* __restrict__ Ctx, const float* __restrict__ W,
    const float* __restrict__ bias, float* __restrict__ Out)
{
    __shared__ short As[128 * 72];
    __shared__ short Bs[128 * 72];

    const int tid  = threadIdx.x;
    const int lane = tid & 63, w = tid >> 6;
    const int wr = w >> 1, wc = w & 1;
    const int l16 = lane & 15, g = lane >> 4;
    const int m0 = blockIdx.x * 128, n0 = blockIdx.y * 128;

    f32x4 acc[4][4];
    #pragma unroll
    for (int i = 0; i < 4; ++i)
        #pragma unroll
        for (int j = 0; j < 4; ++j)
            acc[i][j] = (f32x4){0.f, 0.f, 0.f, 0.f};

    for (int k0 = 0; k0 < Dn; k0 += 64) {
        #pragma unroll
        for (int f = 0; f < 4; ++f) {
            int lin = tid + 256 * f;
            int row = lin >> 3, c8 = lin & 7;
            bf16x8 av = *(const bf16x8*)&Ctx[(size_t)(m0 + row) * Dn + k0 + c8 * 8];
            *(bf16x8*)&As[row * 72 + c8 * 8] = av;
        }
        #pragma unroll
        for (int f = 0; f < 8; ++f) {
            int lin = tid + 256 * f;
            int row = lin >> 4, c4 = lin & 15;
            float4 wv4 = *(const float4*)&W[(size_t)(n0 + row) * Dn + k0 + c4 * 4];
            uint2 wp = {cvt_pk_bf16(wv4.x, wv4.y), cvt_pk_bf16(wv4.z, wv4.w)};
            *(uint2*)&Bs[row * 72 + c4 * 4] = wp;
        }
        __syncthreads();

        bf16x8 af[4][2], bfv[4][2];
        #pragma unroll
        for (int i = 0; i < 4; ++i)
            #pragma unroll
            for (int c = 0; c < 2; ++c)
                af[i][c] = *(const bf16x8*)&As[(wr * 64 + i * 16 + l16) * 72 + c * 32 + g * 8];
        #pragma unroll
        for (int j = 0; j < 4; ++j)
            #pragma unroll
            for (int c = 0; c < 2; ++c)
                bfv[j][c] = *(const bf16x8*)&Bs[(wc * 64 + j * 16 + l16) * 72 + c * 32 + g * 8];

        #pragma unroll
        for (int i = 0; i < 4; ++i)
            #pragma unroll
            for (int j = 0; j < 4; ++j) {
                acc[i][j] = __builtin_amdgcn_mfma_f32_16x16x32_bf16(af[i][0], bfv[j][0], acc[i][j], 0, 0, 0);
                acc[i][j] = __builtin_amdgcn_mfma_f32_16x16x32_bf16(af[i][1], bfv[j][1], acc[i][j], 0, 0, 0);
            }
        __syncthreads();
    }

    #pragma unroll
    for (int i = 0; i < 4; ++i) {
        #pragma unroll
        for (int j = 0; j < 4; ++j) {
            int n = n0 + wc * 64 + j * 16 + l16;
            float bval = bias[n];
            #pragma unroll
            for (int r = 0; r < 4; ++r) {
                int m = m0 + wr * 64 + i * 16 + g * 4 + r;
                Out[(size_t)m * Dn + n] = acc[i][j][r] + bval;
            }
        }
    }
}

// ---------------------------------------------------------------------------
extern "C" void kernel_launch(void* const* d_in, const int* in_sizes, int n_in,
                              void* d_out, int out_size, void* d_ws, size_t ws_size,
                              hipStream_t stream)
{
    (void)in_sizes; (void)n_in; (void)out_size;
    const float* q    = (const float*)d_in[0];
    const float* k    = (const float*)d_in[1];
    const float* v    = (const float*)d_in[2];
    const int*   mks  = (const int*)  d_in[3];
    const float* wq_w = (const float*)d_in[4];
    const float* wq_b = (const float*)d_in[5];
    const float* wk_w = (const float*)d_in[6];
    const float* wk_b = (const float*)d_in[7];
    const float* wv_w = (const float*)d_in[8];
    const float* wv_b = (const float*)d_in[9];
    const float* wo_w = (const float*)d_in[10];
    const float* wo_b = (const float*)d_in[11];
    float* out = (float*)d_out;

    short* ws = (short*)d_ws;
    const size_t needed = (4 * HE + 4 * WN + 2 * (size_t)Bn * Ln) * 2;   // ~36 MiB

    if (ws_size >= needed) {
        short* Qh   = ws;
        short* Kh   = ws + HE;
        short* Vt   = ws + 2 * HE;
        short* Ctx  = ws + 3 * HE;
        short* Wb   = ws + 4 * HE;
        float* maskF = (float*)(ws + 4 * HE + 4 * WN);

        const int prepBlocks = (int)((WN + (size_t)Bn * Ln + 255) / 256);
        prep_wm<<<dim3(prepBlocks), 256, 0, stream>>>(
            wq_w, wk_w, wv_w, wo_w, mks, Wb, maskF);

        qkv_proj_f32<<<dim3(128, 4, 3), 256, 0, stream>>>(
            q, k, v, Wb, wq_b, wk_b, wv_b, Qh, Kh, Vt);

        attn_mfma<<<dim3(1024), 256, 0, stream>>>(Qh, Kh, Vt, maskF, Ctx);

        out_proj_bf16<<<dim3(128, 8), 256, 0, stream>>>(Ctx, Wb + 3 * WN, wo_b, out);
    } else {
        short* Qh  = ws;
        short* Kh  = ws + HE;
        short* Vt  = ws + 2 * HE;
        short* Ctx = ws + 3 * HE;
        float* maskF = (float*)(ws + 4 * HE);

        mask_prep<<<dim3(32), 256, 0, stream>>>(mks, maskF);
        qkv_proj_mfma<<<dim3(Mtot / 128, Dn / 128, 3), 256, 0, stream>>>(
            q, k, v, wq_w, wk_w, wv_w, wq_b, wk_b, wv_b, Qh, Kh, Vt);
        attn_mfma<<<dim3(1024), 256, 0, stream>>>(Qh, Kh, Vt, maskF, Ctx);
        out_proj_mfma<<<dim3(Mtot / 128, Dn / 128), 256, 0, stream>>>(Ctx, wo_w, wo_b, out);
    }
}

// Round 19
// 106.901 us; speedup vs baseline: 1.0665x; 1.0150x over previous
//
#include <hip/hip_runtime.h>
#include <hip/hip_bf16.h>
#include <cstddef>

typedef __attribute__((ext_vector_type(8)))  short bf16x8;
typedef __attribute__((ext_vector_type(4)))  float f32x4;

constexpr int Bn = 4, Ln = 2048, Dn = 512, Hn = 8, DKn = 64, Mtot = 8192;
constexpr float QSCALE = 0.125f * 1.44269504088896341f;   // 1/sqrt(DK) * log2(e)
constexpr size_t HE = (size_t)Bn * Hn * Ln * DKn;          // 4,194,304
constexpr size_t WN = (size_t)Dn * Dn;                     // 262,144

__device__ inline unsigned cvt_pk_bf16(float lo, float hi) {
    unsigned r;
    asm("v_cvt_pk_bf16_f32 %0, %1, %2" : "=v"(r) : "v"(lo), "v"(hi));
    return r;
}
__device__ inline short f2bf(float x) {
    union { float f; unsigned u; } v; v.f = x;
    unsigned r = v.u + 0x7fffu + ((v.u >> 16) & 1u);
    return (short)(r >> 16);
}
__device__ inline void gl_lds16(const short* g, short* l) {
    __builtin_amdgcn_global_load_lds(
        (const __attribute__((address_space(1))) void*)g,
        (__attribute__((address_space(3))) void*)l, 16, 0, 0);
}
__device__ inline void gl_lds16f(const float* g, float* l) {
    __builtin_amdgcn_global_load_lds(
        (const __attribute__((address_space(1))) void*)g,
        (__attribute__((address_space(3))) void*)l, 16, 0, 0);
}

// ---------------------------------------------------------------------------
// Slim prep: cast 4 weights -> bf16, mask -> -1e30/0.  grid 1056 x 256.
// ---------------------------------------------------------------------------
__global__ __launch_bounds__(256) void prep_wm(
    const float* __restrict__ wq, const float* __restrict__ wk,
    const float* __restrict__ wv, const float* __restrict__ wo,
    const int* __restrict__ masks,
    short* __restrict__ Wb, float* __restrict__ maskF)
{
    size_t gid = (size_t)blockIdx.x * 256 + threadIdx.x;
    if (gid < WN) {
        int which = (int)(gid >> 16);
        const float* src = (which == 0) ? wq : (which == 1) ? wk : (which == 2) ? wv : wo;
        size_t i4 = gid & 65535;
        float4 xv = *(const float4*)&src[i4 * 4];
        uint2 p = {cvt_pk_bf16(xv.x, xv.y), cvt_pk_bf16(xv.z, xv.w)};
        *(uint2*)&Wb[(size_t)which * WN + i4 * 4] = p;
    } else {
        size_t mi = gid - WN;
        if (mi < (size_t)Bn * Ln) maskF[mi] = (masks[mi] == 0) ? -1e30f : 0.f;
    }
}

__global__ __launch_bounds__(256) void mask_prep(
    const int* __restrict__ masks, float* __restrict__ maskF)
{
    int i = blockIdx.x * 256 + threadIdx.x;
    if (i < Bn * Ln) maskF[i] = (masks[i] == 0) ? -1e30f : 0.f;
}

// ---------------------------------------------------------------------------
// QKV projection (R17): BM=64 x BN=128, A fp32 DMA + convert-at-read,
// B bf16 DMA.  LDS 32 KB.  grid (128, 4, 3) x 256, 8 K-steps.
// ---------------------------------------------------------------------------
__global__ __launch_bounds__(256) void qkv_proj_f32(
    const float* __restrict__ q, const float* __restrict__ k, const float* __restrict__ v,
    const short* __restrict__ Wb,
    const float* __restrict__ bq, const float* __restrict__ bk, const float* __restrict__ bv,
    short* __restrict__ Qh, short* __restrict__ Kh, short* __restrict__ Vt)
{
    const int p = blockIdx.z;
    const float* X    = (p == 0) ? q : (p == 1) ? k : v;
    const short* W    = Wb + (size_t)p * WN;
    const float* bias = (p == 0) ? bq : (p == 1) ? bk : bv;
    short*       O    = (p == 0) ? Qh : (p == 1) ? Kh : Vt;
    const float scl   = (p == 0) ? QSCALE : 1.0f;

    __shared__ float Af[64 * 64];    // 16 KB
    __shared__ short Bs[128 * 64];   // 16 KB

    const int tid  = threadIdx.x;
    const int lane = tid & 63, w = tid >> 6;
    const int wr = w >> 1, wc = w & 1;
    const int l16 = lane & 15, g = lane >> 4;
    const int m0 = blockIdx.x * 64, n0 = blockIdx.y * 128;

    const int rA = tid >> 4, col4 = tid & 15;
    const int scolA = (col4 * 4) ^ (8 * (rA & 7));
    const float* Ag = X + (size_t)(m0 + rA) * Dn + scolA;
    const int rB = tid >> 3, c8 = tid & 7;
    const int scolB = ((c8 ^ (rB & 7)) << 3);
    const short* Bg = W + (size_t)(n0 + rB) * Dn + scolB;

    f32x4 acc[2][4];
    #pragma unroll
    for (int i = 0; i < 2; ++i)
        #pragma unroll
        for (int j = 0; j < 4; ++j)
            acc[i][j] = (f32x4){0.f, 0.f, 0.f, 0.f};

    for (int ks = 0; ks < 8; ++ks) {
        #pragma unroll
        for (int f = 0; f < 4; ++f)
            gl_lds16f(Ag + (size_t)f * 16 * Dn, &Af[(w * 64 + 256 * f) * 4]);
        #pragma unroll
        for (int f = 0; f < 4; ++f)
            gl_lds16(Bg + (size_t)f * 32 * Dn, &Bs[(w * 64 + 256 * f) * 8]);
        Ag += 64; Bg += 64;
        __syncthreads();

        bf16x8 bfv[4][2];
        #pragma unroll
        for (int j = 0; j < 4; ++j) {
            int row = wc * 64 + j * 16 + l16;
            int sw = (row & 7) << 3;
            bfv[j][0] = *(const bf16x8*)&Bs[row * 64 + ((g * 8) ^ sw)];
            bfv[j][1] = *(const bf16x8*)&Bs[row * 64 + ((32 + g * 8) ^ sw)];
        }
        #pragma unroll
        for (int i = 0; i < 2; ++i) {
            int row = wr * 32 + i * 16 + l16;
            int m8 = 8 * (row & 7);
            bf16x8 a[2];
            #pragma unroll
            for (int c = 0; c < 2; ++c) {
                int base = row * 64 + ((g * 8 + c * 32) ^ m8);
                f32x4 x0 = *(const f32x4*)&Af[base];
                f32x4 x1 = *(const f32x4*)&Af[base + 4];
                union { unsigned u[4]; bf16x8 v; } pu;
                pu.u[0] = cvt_pk_bf16(x0[0], x0[1]);
                pu.u[1] = cvt_pk_bf16(x0[2], x0[3]);
                pu.u[2] = cvt_pk_bf16(x1[0], x1[1]);
                pu.u[3] = cvt_pk_bf16(x1[2], x1[3]);
                a[c] = pu.v;
            }
            #pragma unroll
            for (int j = 0; j < 4; ++j) {
                acc[i][j] = __builtin_amdgcn_mfma_f32_16x16x32_bf16(a[0], bfv[j][0], acc[i][j], 0, 0, 0);
                acc[i][j] = __builtin_amdgcn_mfma_f32_16x16x32_bf16(a[1], bfv[j][1], acc[i][j], 0, 0, 0);
            }
        }
        __syncthreads();
    }

    const int bb = m0 >> 11;
    #pragma unroll
    for (int i = 0; i < 2; ++i) {
        #pragma unroll
        for (int j = 0; j < 4; ++j) {
            int n  = n0 + wc * 64 + j * 16 + l16;
            int h  = n >> 6, dk = n & 63;
            float bval = bias[n];
            #pragma unroll
            for (int r = 0; r < 4; ++r) {
                int m  = m0 + wr * 32 + i * 16 + g * 4 + r;
                int lq = m & (Ln - 1);
                short val = f2bf((acc[i][j][r] + bval) * scl);
                if (p < 2)
                    O[(((size_t)bb * Hn + h) * Ln + lq) * DKn + dk] = val;
                else
                    O[(((size_t)bb * Hn + h) * DKn + dk) * Ln + lq] = val;
            }
        }
    }
}

// ---------------------------------------------------------------------------
// Output projection (R18): 64x64 tile, double-buffered DMA.  grid (128,8).
// ---------------------------------------------------------------------------
__global__ __launch_bounds__(256) void out_proj_bf16(
    const short* __restrict__ Ctx, const short* __restrict__ Wo,
    const float* __restrict__ bias, float* __restrict__ Out)
{
    __shared__ short As[2][64 * 64];
    __shared__ short Bs[2][64 * 64];

    const int tid  = threadIdx.x;
    const int lane = tid & 63, w = tid >> 6;
    const int wr = w >> 1, wc = w & 1;
    const int l16 = lane & 15, g = lane >> 4;
    const int m0 = blockIdx.x * 64, n0 = blockIdx.y * 64;

    const short* Ag[2]; const short* Bg[2]; int ldsOff[2];
    #pragma unroll
    for (int f = 0; f < 2; ++f) {
        int c = tid + 256 * f;
        int row = c >> 3, col8 = c & 7;
        int scolw = ((col8 ^ (row & 7)) << 3);
        Ag[f] = Ctx + (size_t)(m0 + row) * Dn + scolw;
        Bg[f] = Wo  + (size_t)(n0 + row) * Dn + scolw;
        ldsOff[f] = (w * 64 + 256 * f) * 8;
    }

    f32x4 acc[2][2];
    #pragma unroll
    for (int i = 0; i < 2; ++i)
        #pragma unroll
        for (int j = 0; j < 2; ++j)
            acc[i][j] = (f32x4){0.f, 0.f, 0.f, 0.f};

    #pragma unroll
    for (int f = 0; f < 2; ++f) {
        gl_lds16(Ag[f], &As[0][ldsOff[f]]);
        gl_lds16(Bg[f], &Bs[0][ldsOff[f]]);
        Ag[f] += 64; Bg[f] += 64;
    }
    __syncthreads();

    int cb = 0;
    for (int ks = 0; ks < 8; ++ks) {
        if (ks < 7) {
            #pragma unroll
            for (int f = 0; f < 2; ++f) {
                gl_lds16(Ag[f], &As[cb ^ 1][ldsOff[f]]);
                gl_lds16(Bg[f], &Bs[cb ^ 1][ldsOff[f]]);
                Ag[f] += 64; Bg[f] += 64;
            }
        }

        bf16x8 bfv[2][2];
        #pragma unroll
        for (int j = 0; j < 2; ++j) {
            int row = wc * 32 + j * 16 + l16;
            int sw = (row & 7) << 3;
            bfv[j][0] = *(const bf16x8*)&Bs[cb][row * 64 + ((g * 8) ^ sw)];
            bfv[j][1] = *(const bf16x8*)&Bs[cb][row * 64 + ((32 + g * 8) ^ sw)];
        }
        #pragma unroll
        for (int i = 0; i < 2; ++i) {
            int row = wr * 32 + i * 16 + l16;
            int sw = (row & 7) << 3;
            bf16x8 a0 = *(const bf16x8*)&As[cb][row * 64 + ((g * 8) ^ sw)];
            bf16x8 a1 = *(const bf16x8*)&As[cb][row * 64 + ((32 + g * 8) ^ sw)];
            #pragma unroll
            for (int j = 0; j < 2; ++j) {
                acc[i][j] = __builtin_amdgcn_mfma_f32_16x16x32_bf16(a0, bfv[j][0], acc[i][j], 0, 0, 0);
                acc[i][j] = __builtin_amdgcn_mfma_f32_16x16x32_bf16(a1, bfv[j][1], acc[i][j], 0, 0, 0);
            }
        }
        __syncthreads();
        cb ^= 1;
    }

    #pragma unroll
    for (int i = 0; i < 2; ++i) {
        #pragma unroll
        for (int j = 0; j < 2; ++j) {
            int n = n0 + wc * 32 + j * 16 + l16;
            float bval = bias[n];
            #pragma unroll
            for (int r = 0; r < 4; ++r) {
                int m = m0 + wr * 32 + i * 16 + g * 4 + r;
                Out[(size_t)m * Dn + n] = acc[i][j][r] + bval;
            }
        }
    }
}

// ---------------------------------------------------------------------------
// Flash attention v19: R18 structure with the NT loop hand-unrolled x2
// (literal buffer indices) and V-fragment LDS reads hoisted to the top of
// the tile body (drain under QK^T + softmax).
// ---------------------------------------------------------------------------
__global__ __launch_bounds__(256, 3) void attn_mfma(
    const short* __restrict__ Qh, const short* __restrict__ Kh, const short* __restrict__ Vt,
    const float* __restrict__ maskF, short* __restrict__ Ctx)
{
    __shared__ short smem[16384];

    const int tid  = threadIdx.x;
    const int lane = tid & 63, w = tid >> 6;
    const int l16 = lane & 15, g = lane >> 4;
    const int qt = w & 1, hf = w >> 1;

    const int bid = blockIdx.x;
    const int id  = (bid & 7) * 128 + (bid >> 3);
    const int qb  = id & 31;
    const int bh  = id >> 5;
    const int bb  = bh >> 3, hd = bh & 7;
    const int q0  = qb * 64;
    constexpr int NT = 32;

    const short* Qp = Qh + (size_t)bh * Ln * DKn;
    const short* Kp = Kh + (size_t)bh * Ln * DKn;
    const short* Vp = Vt + (size_t)bh * DKn * Ln;
    const float* mp = maskF + bb * Ln + hf * 1024;

    bf16x8 qf[2][2];
    #pragma unroll
    for (int mf = 0; mf < 2; ++mf)
        #pragma unroll
        for (int c = 0; c < 2; ++c)
            qf[mf][c] = *(const bf16x8*)&Qp[(size_t)(q0 + qt * 32 + mf * 16 + l16) * DKn + c * 32 + g * 8];

    constexpr short BF1 = (short)0x3F80;
    const bf16x8 ones = {BF1, BF1, BF1, BF1, BF1, BF1, BF1, BF1};

    const short* kg[2]; const short* vg[2]; int sbk[2];
    #pragma unroll
    for (int j = 0; j < 2; ++j) {
        int sb = qt * 2 + j;
        sbk[j] = sb * 512;
        int p  = sb * 8 + (lane >> 3);
        int kc = ((p & 0x0C) << 1) | ((p & 0x10) >> 2) | (p & 3);
        int scol = ((lane & 7) ^ (p & 7)) << 3;
        kg[j] = Kp + (size_t)(hf * 1024 + kc) * DKn + scol;
        int vrow = sb * 16 + (lane >> 2);
        int scolv = (((lane & 3) ^ (vrow & 3)) << 3);
        vg[j] = Vp + (size_t)vrow * Ln + hf * 1024 + scolv;
    }

    int kofs[2][2];
    #pragma unroll
    for (int kt = 0; kt < 2; ++kt) {
        int row = kt * 16 + l16;
        kofs[kt][0] = row * 64 + ((g * 8) ^ ((row & 7) << 3));
        kofs[kt][1] = row * 64 + ((32 + g * 8) ^ ((row & 7) << 3));
    }
    int vofs[4];
    #pragma unroll
    for (int d = 0; d < 4; ++d)
        vofs[d] = (d * 16 + l16) * 32 + ((g * 8) ^ ((l16 & 3) << 3));

    f32x4 oacc[2][4];
    #pragma unroll
    for (int mf = 0; mf < 2; ++mf)
        #pragma unroll
        for (int d = 0; d < 4; ++d) oacc[mf][d] = (f32x4){0.f, 0.f, 0.f, 0.f};
    f32x4 lsum[2] = {(f32x4){0.f, 0.f, 0.f, 0.f}, (f32x4){0.f, 0.f, 0.f, 0.f}};

    #pragma unroll
    for (int j = 0; j < 2; ++j) {
        gl_lds16(kg[j], smem + hf * 4096 + sbk[j]);
        gl_lds16(vg[j], smem + 8192 + hf * 4096 + sbk[j]);
    }
    f32x4 mkA0 = *(const f32x4*)&mp[8 * g];
    f32x4 mkA1 = *(const f32x4*)&mp[8 * g + 4];
    __syncthreads();

    // tile body: cbuf is a LITERAL at each call site -> all LDS addresses fold
    auto tile_body = [&](int t, int cbuf) {
        if (t < NT - 1) {
            const int ko = (t + 1) * 2048;
            const int vo = (t + 1) * 32;
            short* kd = smem + (hf * 2 + (cbuf ^ 1)) * 2048;
            short* vd = smem + 8192 + (hf * 2 + (cbuf ^ 1)) * 2048;
            #pragma unroll
            for (int j = 0; j < 2; ++j) {
                gl_lds16(kg[j] + ko, kd + sbk[j]);
                gl_lds16(vg[j] + vo, vd + sbk[j]);
            }
        }
        const short* Kb = smem + (hf * 2 + cbuf) * 2048;
        const short* Vb = smem + 8192 + (hf * 2 + cbuf) * 2048;

        // V frags issued FIRST: drain under QK^T + softmax
        bf16x8 vf[4];
        #pragma unroll
        for (int d = 0; d < 4; ++d)
            vf[d] = *(const bf16x8*)&Vb[vofs[d]];

        f32x4 mk[2] = {mkA0, mkA1};
        if (t < NT - 1) {
            mkA0 = *(const f32x4*)&mp[(t + 1) * 32 + 8 * g];
            mkA1 = *(const f32x4*)&mp[(t + 1) * 32 + 8 * g + 4];
        }

        bf16x8 kf[2][2];
        #pragma unroll
        for (int kt = 0; kt < 2; ++kt) {
            kf[kt][0] = *(const bf16x8*)&Kb[kofs[kt][0]];
            kf[kt][1] = *(const bf16x8*)&Kb[kofs[kt][1]];
        }

        f32x4 sv[2][2];
        __builtin_amdgcn_s_setprio(1);
        #pragma unroll
        for (int mf = 0; mf < 2; ++mf)
            #pragma unroll
            for (int kt = 0; kt < 2; ++kt) {
                f32x4 z = __builtin_amdgcn_mfma_f32_16x16x32_bf16(kf[kt][0], qf[mf][0], mk[kt], 0, 0, 0);
                z = __builtin_amdgcn_mfma_f32_16x16x32_bf16(kf[kt][1], qf[mf][1], z, 0, 0, 0);
                sv[mf][kt] = z;
            }
        __builtin_amdgcn_s_setprio(0);

        bf16x8 pf[2];
        #pragma unroll
        for (int mf = 0; mf < 2; ++mf) {
            float e0 = exp2f(sv[mf][0][0]), e1 = exp2f(sv[mf][0][1]);
            float e2 = exp2f(sv[mf][0][2]), e3 = exp2f(sv[mf][0][3]);
            float e4 = exp2f(sv[mf][1][0]), e5 = exp2f(sv[mf][1][1]);
            float e6 = exp2f(sv[mf][1][2]), e7 = exp2f(sv[mf][1][3]);
            union { unsigned u[4]; bf16x8 v; } pu;
            pu.u[0] = cvt_pk_bf16(e0, e1);
            pu.u[1] = cvt_pk_bf16(e2, e3);
            pu.u[2] = cvt_pk_bf16(e4, e5);
            pu.u[3] = cvt_pk_bf16(e6, e7);
            pf[mf] = pu.v;
        }

        __builtin_amdgcn_s_setprio(1);
        #pragma unroll
        for (int mf = 0; mf < 2; ++mf) {
            lsum[mf] = __builtin_amdgcn_mfma_f32_16x16x32_bf16(ones, pf[mf], lsum[mf], 0, 0, 0);
            #pragma unroll
            for (int d = 0; d < 4; ++d)
                oacc[mf][d] = __builtin_amdgcn_mfma_f32_16x16x32_bf16(vf[d], pf[mf], oacc[mf][d], 0, 0, 0);
        }
        __builtin_amdgcn_s_setprio(0);

        __syncthreads();
    };

    for (int t = 0; t < NT; t += 2) {
        tile_body(t, 0);
        tile_body(t + 1, 1);
    }

    float* M = (float*)smem;
    if (hf == 1) {
        #pragma unroll
        for (int mf = 0; mf < 2; ++mf) {
            int ql = qt * 32 + mf * 16 + l16;
            #pragma unroll
            for (int d = 0; d < 4; ++d)
                *(f32x4*)&M[ql * 68 + d * 16 + g * 4] = oacc[mf][d];
            if (g == 0) M[ql * 68 + 64] = lsum[mf][0];
        }
    }
    __syncthreads();
    if (hf == 0) {
        #pragma unroll
        for (int mf = 0; mf < 2; ++mf) {
            int ql = qt * 32 + mf * 16 + l16;
            float lt = lsum[mf][0] + M[ql * 68 + 64];
            float inv = 1.0f / lt;
            size_t mrow = (size_t)bb * Ln + q0 + ql;
            #pragma unroll
            for (int d = 0; d < 4; ++d) {
                f32x4 ob = *(const f32x4*)&M[ql * 68 + d * 16 + g * 4];
                float o0 = (oacc[mf][d][0] + ob[0]) * inv;
                float o1 = (oacc[mf][d][1] + ob[1]) * inv;
                float o2 = (oacc[mf][d][2] + ob[2]) * inv;
                float o3 = (oacc[mf][d][3] + ob[3]) * inv;
                uint2 pr = {cvt_pk_bf16(o0, o1), cvt_pk_bf16(o2, o3)};
                *(uint2*)&Ctx[mrow * Dn + hd * 64 + d * 16 + g * 4] = pr;
            }
        }
    }
}

// ---------------------------------------------------------------------------
// Fallback kernels (fp32-input projections) for small workspaces.
// ---------------------------------------------------------------------------
__global__ __launch_bounds__(256) void qkv_proj_mfma(
    const float* __restrict__ q, const float* __restrict__ k, const float* __restrict__ v,
    const float* __restrict__ wq, const float* __restrict__ wk, const float* __restrict__ wv,
    const float* __restrict__ bq, const float* __restrict__ bk, const float* __restrict__ bv,
    short* __restrict__ Qh, short* __restrict__ Kh, short* __restrict__ Vt)
{
    const int p = blockIdx.z;
    const float* X    = (p == 0) ? q  : (p == 1) ? k  : v;
    const float* W    = (p == 0) ? wq : (p == 1) ? wk : wv;
    const float* bias = (p == 0) ? bq : (p == 1) ? bk : bv;
    short*       O    = (p == 0) ? Qh : (p == 1) ? Kh : Vt;
    const float scl   = (p == 0) ? QSCALE : 1.0f;

    __shared__ short As[128 * 72];
    __shared__ short Bs[128 * 72];

    const int tid  = threadIdx.x;
    const int lane = tid & 63, w = tid >> 6;
    const int wr = w >> 1, wc = w & 1;
    const int l16 = lane & 15, g = lane >> 4;
    const int m0 = blockIdx.x * 128, n0 = blockIdx.y * 128;

    f32x4 acc[4][4];
    #pragma unroll
    for (int i = 0; i < 4; ++i)
        #pragma unroll
        for (int j = 0; j < 4; ++j)
            acc[i][j] = (f32x4){0.f, 0.f, 0.f, 0.f};

    for (int k0 = 0; k0 < Dn; k0 += 64) {
        #pragma unroll
        for (int f = 0; f < 8; ++f) {
            int lin = tid + 256 * f;
            int row = lin >> 4, c4 = lin & 15;
            float4 xv = *(const float4*)&X[(size_t)(m0 + row) * Dn + k0 + c4 * 4];
            uint2 xp = {cvt_pk_bf16(xv.x, xv.y), cvt_pk_bf16(xv.z, xv.w)};
            *(uint2*)&As[row * 72 + c4 * 4] = xp;
            float4 wv4 = *(const float4*)&W[(size_t)(n0 + row) * Dn + k0 + c4 * 4];
            uint2 wp = {cvt_pk_bf16(wv4.x, wv4.y), cvt_pk_bf16(wv4.z, wv4.w)};
            *(uint2*)&Bs[row * 72 + c4 * 4] = wp;
        }
        __syncthreads();

        bf16x8 af[4][2], bfv[4][2];
        #pragma unroll
        for (int i = 0; i < 4; ++i)
            #pragma unroll
            for (int c = 0; c < 2; ++c)
                af[i][c] = *(const bf16x8*)&As[(wr * 64 + i * 16 + l16) * 72 + c * 32 + g * 8];
        #pragma unroll
        for (int j = 0; j < 4; ++j)
            #pragma unroll
            for (int c = 0; c < 2; ++c)
                bfv[j][c] = *(const bf16x8*)&Bs[(wc * 64 + j * 16 + l16) * 72 + c * 32 + g * 8];

        #pragma unroll
        for (int i = 0; i < 4; ++i)
            #pragma unroll
            for (int j = 0; j < 4; ++j) {
                acc[i][j] = __builtin_amdgcn_mfma_f32_16x16x32_bf16(af[i][0], bfv[j][0], acc[i][j], 0, 0, 0);
                acc[i][j] = __builtin_amdgcn_mfma_f32_16x16x32_bf16(af[i][1], bfv[j][1], acc[i][j], 0, 0, 0);
            }
        __syncthreads();
    }

    const int bb = m0 >> 11;
    #pragma unroll
    for (int i = 0; i < 4; ++i) {
        #pragma unroll
        for (int j = 0; j < 4; ++j) {
            int n  = n0 + wc * 64 + j * 16 + l16;
            int h  = n >> 6, dk = n & 63;
            float bval = bias[n];
            #pragma unroll
            for (int r = 0; r < 4; ++r) {
                int m  = m0 + wr * 64 + i * 16 + g * 4 + r;
                int lq = m & (Ln - 1);
                short val = f2bf((acc[i][j][r] + bval) * scl);
                if (p < 2)
                    O[(((size_t)bb * Hn + h) * Ln + lq) * DKn + dk] = val;
                else
                    O[(((size_t)bb * Hn + h) * DKn + dk) * Ln + lq] = val;
            }
        }
    }
}

__global__ __launch_bounds__(256) void out_proj_mfma(
    const short* __restrict__ Ctx, const float* __restrict__ W,
    const float* __restrict__ bias, float* __restrict__ Out)
{
    __shared__ short As[128 * 72];
    __shared__ short Bs[128 * 72];

    const int tid  = threadIdx.x;
    const int lane = tid & 63, w = tid >> 6;
    const int wr = w >> 1, wc = w & 1;
    const int l16 = lane & 15, g = lane >> 4;
    const int m0 = blockIdx.x * 128, n0 = blockIdx.y * 128;

    f32x4 acc[4][4];
    #pragma unroll
    for (int i = 0; i < 4; ++i)
        #pragma unroll
        for (int j = 0; j < 4; ++j)
            acc[i][j] = (f32x4){0.f, 0.f, 0.f, 0.f};

    for (int k0 = 0; k0 < Dn; k0 += 64) {
        #pragma unroll
        for (int f = 0; f < 4; ++f) {
            int lin = tid + 256 * f;
            int row = lin >> 3, c8 = lin & 7;
            bf16x8 av = *(const bf16x8*)&Ctx[(size_t)(m0 + row) * Dn + k0 + c8 * 8];
            *(bf16x8*)&As[row * 72 + c8 * 8] = av;
        }
        #pragma unroll
        for (int f = 0; f < 8; ++f) {
            int lin = tid + 256 * f;
            int row = lin >> 4, c4 = lin & 15;
            float4 wv4 = *(const float4*)&W[(size_t)(n0 + row) * Dn + k0 + c4 * 4];
            uint2 wp = {cvt_pk_bf16(wv4.x, wv4.y), cvt_pk_bf16(wv4.z, wv4.w)};
            *(uint2*)&Bs[row * 72 + c4 * 4] = wp;
        }
        __syncthreads();

        bf16x8 af[4][2], bfv[4][2];
        #pragma unroll
        for (int i = 0; i < 4; ++i)
            #pragma unroll
            for (int c = 0; c < 2; ++c)
                af[i][c] = *(const bf16x8*)&As[(wr * 64 + i * 16 + l16) * 72 + c * 32 + g * 8];
        #pragma unroll
        for (int j = 0; j < 4; ++j)
            #pragma unroll
            for (int c = 0; c < 2; ++c)
                bfv[j][c] = *(const bf16x8*)&Bs[(wc * 64 + j * 16 + l16) * 72 + c * 32 + g * 8];

        #pragma unroll
        for (int i = 0; i < 4; ++i)
            #pragma unroll
            for (int j = 0; j < 4; ++j) {
                acc[i][j] = __builtin_amdgcn_mfma_f32_16x16x32_bf16(af[i][0], bfv[j][0], acc[i][j], 0, 0, 0);
                acc[i][j] = __builtin_amdgcn_mfma_f32_16x16x32_bf16(af[i][1], bfv[j][1], acc[i][j], 0, 0, 0);
            }
        __syncthreads();
    }

    #pragma unroll
    for (int i = 0; i < 4; ++i) {
        #pragma unroll
        for (int j = 0; j < 4; ++j) {
            int n = n0 + wc * 64 + j * 16 + l16;
            float bval = bias[n];
            #pragma unroll
            for (int r = 0; r < 4; ++r) {
                int m = m0 + wr * 64 + i * 16 + g * 4 + r;
                Out[(size_t)m * Dn + n] = acc[i][j][r] + bval;
            }
        }
    }
}

// ---------------------------------------------------------------------------
extern "C" void kernel_launch(void* const* d_in, const int* in_sizes, int n_in,
                              void* d_out, int out_size, void* d_ws, size_t ws_size,
                              hipStream_t stream)
{
    (void)in_sizes; (void)n_in; (void)out_size;
    const float* q    = (const float*)d_in[0];
    const float* k    = (const float*)d_in[1];
    const float* v    = (const float*)d_in[2];
    const int*   mks  = (const int*)  d_in[3];
    const float* wq_w = (const float*)d_in[4];
    const float* wq_b = (const float*)d_in[5];
    const float* wk_w = (const float*)d_in[6];
    const float* wk_b = (const float*)d_in[7];
    const float* wv_w = (const float*)d_in[8];
    const float* wv_b = (const float*)d_in[9];
    const float* wo_w = (const float*)d_in[10];
    const float* wo_b = (const float*)d_in[11];
    float* out = (float*)d_out;

    short* ws = (short*)d_ws;
    const size_t needed = (4 * HE + 4 * WN + 2 * (size_t)Bn * Ln) * 2;   // ~36 MiB

    if (ws_size >= needed) {
        short* Qh   = ws;
        short* Kh   = ws + HE;
        short* Vt   = ws + 2 * HE;
        short* Ctx  = ws + 3 * HE;
        short* Wb   = ws + 4 * HE;
        float* maskF = (float*)(ws + 4 * HE + 4 * WN);

        const int prepBlocks = (int)((WN + (size_t)Bn * Ln + 255) / 256);
        prep_wm<<<dim3(prepBlocks), 256, 0, stream>>>(
            wq_w, wk_w, wv_w, wo_w, mks, Wb, maskF);

        qkv_proj_f32<<<dim3(128, 4, 3), 256, 0, stream>>>(
            q, k, v, Wb, wq_b, wk_b, wv_b, Qh, Kh, Vt);

        attn_mfma<<<dim3(1024), 256, 0, stream>>>(Qh, Kh, Vt, maskF, Ctx);

        out_proj_bf16<<<dim3(128, 8), 256, 0, stream>>>(Ctx, Wb + 3 * WN, wo_b, out);
    } else {
        short* Qh  = ws;
        short* Kh  = ws + HE;
        short* Vt  = ws + 2 * HE;
        short* Ctx = ws + 3 * HE;
        float* maskF = (float*)(ws + 4 * HE);

        mask_prep<<<dim3(32), 256, 0, stream>>>(mks, maskF);
        qkv_proj_mfma<<<dim3(Mtot / 128, Dn / 128, 3), 256, 0, stream>>>(
            q, k, v, wq_w, wk_w, wv_w, wq_b, wk_b, wv_b, Qh, Kh, Vt);
        attn_mfma<<<dim3(1024), 256, 0, stream>>>(Qh, Kh, Vt, maskF, Ctx);
        out_proj_mfma<<<dim3(Mtot / 128, Dn / 128), 256, 0, stream>>>(Ctx, wo_w, wo_b, out);
    }
}